// Round 4
// baseline (1140.904 us; speedup 1.0000x reference)
//
#include <hip/hip_runtime.h>
#include <hip/hip_bf16.h>

// ---------------------------------------------------------------------------
// CSR build: histogram of dst, exclusive scan, scatter (src, edge_attr).
// edge_index arrives as int32 (harness converts int64 -> int32), shape [2,E].
// All indices defensively clamped so a bad buffer can never fault the GPU.
// ---------------------------------------------------------------------------
__device__ __forceinline__ int clampi(int v, int lo, int hi) {
    return v < lo ? lo : (v > hi ? hi : v);
}

__global__ void hist_kernel(const int* __restrict__ ei, int* __restrict__ count,
                            int E, int n) {
    int j = blockIdx.x * blockDim.x + threadIdx.x;
    if (j < E) {
        int d = clampi(ei[E + j], 0, n - 1);
        atomicAdd(&count[d], 1);
    }
}

__global__ void scan_exclusive(const int* __restrict__ count, int* __restrict__ row_ptr,
                               int* __restrict__ cursor, int n) {
    __shared__ int wsum[16];
    int tid = threadIdx.x;            // blockDim.x == 1024 (16 waves)
    int lane = tid & 63, wv = tid >> 6;
    int carry = 0;
    for (int base = 0; base < n; base += 1024) {
        int i = base + tid;
        int v = (i < n) ? count[i] : 0;
        int sv = v;
        #pragma unroll
        for (int off = 1; off < 64; off <<= 1) {
            int t = __shfl_up(sv, off, 64);
            if (lane >= off) sv += t;
        }
        if (lane == 63) wsum[wv] = sv;
        __syncthreads();
        if (tid < 16) {
            int ws = wsum[tid];
            #pragma unroll
            for (int off = 1; off < 16; off <<= 1) {
                int t = __shfl_up(ws, off, 64);
                if (tid >= off) ws += t;
            }
            wsum[tid] = ws;
        }
        __syncthreads();
        int addv = carry + (wv ? wsum[wv - 1] : 0);
        if (i < n) {
            int ex = addv + sv - v;
            row_ptr[i] = ex;
            cursor[i] = ex;
        }
        carry += wsum[15];
        __syncthreads();
    }
    if (tid == 0) row_ptr[n] = carry;
}

__global__ void scatter_kernel(const int* __restrict__ ei, const float* __restrict__ ea,
                               int* __restrict__ cursor, int* __restrict__ csr_src,
                               float* __restrict__ csr_ea, int E, int n) {
    int j = blockIdx.x * blockDim.x + threadIdx.x;
    if (j < E) {
        int d = clampi(ei[E + j], 0, n - 1);
        int pos = atomicAdd(&cursor[d], 1);
        if (pos >= 0 && pos < E) {
            csr_src[pos] = clampi(ei[j], 0, n - 1);
            csr_ea[pos] = ea[j];
        }
    }
}

// ---------------------------------------------------------------------------
// Node transform: Q = x@Wq+bq, K = x@Wk+bk, V = x@Wv+bv, S = x@Ws+bs,
// qWe[i] = dot(Q[i], We). Weights interleaved as float4 in LDS; 4 rows/wave.
// ---------------------------------------------------------------------------
__global__ __launch_bounds__(256) void node_transform(
    const float* __restrict__ xin,
    const float* __restrict__ Wq, const float* __restrict__ bq,
    const float* __restrict__ Wk, const float* __restrict__ bk,
    const float* __restrict__ Wv, const float* __restrict__ bv,
    const float* __restrict__ Ws, const float* __restrict__ bs,
    const float* __restrict__ We,
    float* __restrict__ Q, float* __restrict__ K, float* __restrict__ V,
    float* __restrict__ S, float* __restrict__ qWe, int n)
{
    __shared__ float4 w[64 * 64];     // 64 KiB: {Wq,Wk,Wv,Ws}[k][d]
    __shared__ float4 bias[64];
    for (int idx = threadIdx.x; idx < 4096; idx += blockDim.x)
        w[idx] = make_float4(Wq[idx], Wk[idx], Wv[idx], Ws[idx]);
    if (threadIdx.x < 64)
        bias[threadIdx.x] = make_float4(bq[threadIdx.x], bk[threadIdx.x],
                                        bv[threadIdx.x], bs[threadIdx.x]);
    __syncthreads();

    int lane = threadIdx.x & 63;
    int wid = (blockIdx.x * blockDim.x + threadIdx.x) >> 6;
    int nw  = (gridDim.x * blockDim.x) >> 6;
    float we_d = We[lane];
    float4 bb = bias[lane];

    for (int r0 = wid * 4; r0 < n; r0 += nw * 4) {
        float aq[4], ak[4], av[4], as_[4];
        #pragma unroll
        for (int r = 0; r < 4; ++r) { aq[r] = bb.x; ak[r] = bb.y; av[r] = bb.z; as_[r] = bb.w; }

        #pragma unroll
        for (int kk = 0; kk < 16; ++kk) {
            float4 xv[4];
            #pragma unroll
            for (int r = 0; r < 4; ++r) {
                int rr = r0 + r; if (rr >= n) rr = n - 1;
                xv[r] = ((const float4*)(xin + (size_t)rr * 64))[kk];
            }
            #pragma unroll
            for (int t = 0; t < 4; ++t) {
                float4 wv = w[(kk * 4 + t) * 64 + lane];
                #pragma unroll
                for (int r = 0; r < 4; ++r) {
                    float xs = (t == 0) ? xv[r].x : (t == 1) ? xv[r].y : (t == 2) ? xv[r].z : xv[r].w;
                    aq[r]  += xs * wv.x;
                    ak[r]  += xs * wv.y;
                    av[r]  += xs * wv.z;
                    as_[r] += xs * wv.w;
                }
            }
        }

        #pragma unroll
        for (int r = 0; r < 4; ++r) {
            int rr = r0 + r;
            if (rr >= n) break;
            float part = aq[r] * we_d;
            part += __shfl_xor(part, 1);
            part += __shfl_xor(part, 2);
            part += __shfl_xor(part, 4);
            part += __shfl_xor(part, 8);
            part += __shfl_xor(part, 16);
            part += __shfl_xor(part, 32);
            if (lane == 0) qWe[rr] = part;
            size_t o = (size_t)rr * 64 + lane;
            Q[o] = aq[r]; K[o] = ak[r]; V[o] = av[r]; S[o] = as_[r];
        }
    }
}

// ---------------------------------------------------------------------------
// Aggregation: one wave per dst node. 4 groups x 16 lanes; each group handles
// one edge per iteration; lane q16 holds quarter-row float4 of K/V rows.
// score = (Q[dst].K[src] + ea*qWe[dst]) / 8 ; softmax w/o max-subtraction
// (scores are O(1): softmax is shift-invariant, no overflow risk).
// out = sum(p * (V[src] + ea*We)) / sum(p) + S[dst]  (+ optional relu).
// ---------------------------------------------------------------------------
__global__ __launch_bounds__(256) void agg_kernel(
    const float* __restrict__ Q, const float* __restrict__ Km, const float* __restrict__ Vm,
    const float* __restrict__ S, const float* __restrict__ qWe, const float* __restrict__ We,
    const int* __restrict__ row_ptr, const int* __restrict__ csr_src,
    const float* __restrict__ csr_ea, float* __restrict__ out, int n, int E, int do_relu)
{
    int lane = threadIdx.x & 63;
    int g = lane >> 4;        // edge slot within iteration
    int q16 = lane & 15;      // quarter-row index
    int wid = (blockIdx.x * blockDim.x + threadIdx.x) >> 6;
    int nw  = (gridDim.x * blockDim.x) >> 6;
    float4 we4 = ((const float4*)We)[q16];

    for (int i = wid; i < n; i += nw) {
        int beg = clampi(row_ptr[i], 0, E);
        int end = clampi(row_ptr[i + 1], beg, E);
        float4 qv = ((const float4*)(Q + (size_t)i * 64))[q16];
        float qwe = qWe[i] * 0.125f;
        float4 acc = make_float4(0.f, 0.f, 0.f, 0.f);
        float ssum = 0.f;

        for (int e0 = beg; e0 < end; e0 += 4) {
            int eidx = e0 + g;
            bool valid = (eidx < end);
            int idx = valid ? eidx : beg;
            int sp = clampi(csr_src[idx], 0, n - 1);
            float ea = csr_ea[idx];
            float4 kv = ((const float4*)(Km + (size_t)sp * 64))[q16];
            float part = qv.x * kv.x + qv.y * kv.y + qv.z * kv.z + qv.w * kv.w;
            part += __shfl_xor(part, 1);
            part += __shfl_xor(part, 2);
            part += __shfl_xor(part, 4);
            part += __shfl_xor(part, 8);
            float score = part * 0.125f + ea * qwe;
            float p = valid ? __expf(score) : 0.f;
            ssum += p;
            float4 vv = ((const float4*)(Vm + (size_t)sp * 64))[q16];
            acc.x += p * (vv.x + ea * we4.x);
            acc.y += p * (vv.y + ea * we4.y);
            acc.z += p * (vv.z + ea * we4.z);
            acc.w += p * (vv.w + ea * we4.w);
        }

        // combine the 4 groups (lanes with equal q16 exchange via xor 16,32)
        ssum += __shfl_xor(ssum, 16); ssum += __shfl_xor(ssum, 32);
        acc.x += __shfl_xor(acc.x, 16); acc.x += __shfl_xor(acc.x, 32);
        acc.y += __shfl_xor(acc.y, 16); acc.y += __shfl_xor(acc.y, 32);
        acc.z += __shfl_xor(acc.z, 16); acc.z += __shfl_xor(acc.z, 32);
        acc.w += __shfl_xor(acc.w, 16); acc.w += __shfl_xor(acc.w, 32);

        float inv = (ssum > 0.f) ? 1.f / ssum : 0.f;
        float4 sr = ((const float4*)(S + (size_t)i * 64))[q16];
        float4 o;
        o.x = acc.x * inv + sr.x;
        o.y = acc.y * inv + sr.y;
        o.z = acc.z * inv + sr.z;
        o.w = acc.w * inv + sr.w;
        if (do_relu) {
            o.x = fmaxf(o.x, 0.f); o.y = fmaxf(o.y, 0.f);
            o.z = fmaxf(o.z, 0.f); o.w = fmaxf(o.w, 0.f);
        }
        if (g == 0) ((float4*)(out + (size_t)i * 64))[q16] = o;
    }
}

// ---------------------------------------------------------------------------
extern "C" void kernel_launch(void* const* d_in, const int* in_sizes, int n_in,
                              void* d_out, int out_size, void* d_ws, size_t ws_size,
                              hipStream_t stream) {
    const float* x   = (const float*)d_in[0];
    const int*   ei  = (const int*)d_in[1];     // int32 on device (harness converts)
    const float* ea  = (const float*)d_in[2];
    const float *Wq1 = (const float*)d_in[3],  *bq1 = (const float*)d_in[4];
    const float *Wk1 = (const float*)d_in[5],  *bk1 = (const float*)d_in[6];
    const float *Wv1 = (const float*)d_in[7],  *bv1 = (const float*)d_in[8];
    const float *We1 = (const float*)d_in[9];
    const float *Ws1 = (const float*)d_in[10], *bs1 = (const float*)d_in[11];
    const float *Wq2 = (const float*)d_in[12], *bq2 = (const float*)d_in[13];
    const float *Wk2 = (const float*)d_in[14], *bk2 = (const float*)d_in[15];
    const float *Wv2 = (const float*)d_in[16], *bv2 = (const float*)d_in[17];
    const float *We2 = (const float*)d_in[18];
    const float *Ws2 = (const float*)d_in[19], *bs2 = (const float*)d_in[20];

    const int N_ = in_sizes[0] / 64;   // 50000
    const int E_ = in_sizes[2];        // 800000

    // carve workspace (256B-aligned)
    char* wsb = (char*)d_ws;
    size_t off = 0;
    auto carve = [&](size_t bytes) -> void* {
        void* p = (void*)(wsb + off);
        off += (bytes + 255) & ~(size_t)255;
        return p;
    };
    float* Q    = (float*)carve((size_t)N_ * 64 * 4);
    float* K    = (float*)carve((size_t)N_ * 64 * 4);
    float* V    = (float*)carve((size_t)N_ * 64 * 4);
    float* S    = (float*)carve((size_t)N_ * 64 * 4);
    float* h    = (float*)carve((size_t)N_ * 64 * 4);
    float* qWe  = (float*)carve((size_t)N_ * 4);
    int*   count   = (int*)carve((size_t)N_ * 4);
    int*   row_ptr = (int*)carve((size_t)(N_ + 1) * 4);
    int*   cursor  = (int*)carve((size_t)N_ * 4);
    int*   csr_src = (int*)carve((size_t)E_ * 4);
    float* csr_ea  = (float*)carve((size_t)E_ * 4);
    (void)ws_size; (void)n_in; (void)out_size;

    // CSR build (shared by both layers)
    hipMemsetAsync(count, 0, (size_t)N_ * 4, stream);
    int eb = (E_ + 255) / 256;
    hist_kernel<<<eb, 256, 0, stream>>>(ei, count, E_, N_);
    scan_exclusive<<<1, 1024, 0, stream>>>(count, row_ptr, cursor, N_);
    scatter_kernel<<<eb, 256, 0, stream>>>(ei, ea, cursor, csr_src, csr_ea, E_, N_);

    // Layer 1
    node_transform<<<512, 256, 0, stream>>>(x, Wq1, bq1, Wk1, bk1, Wv1, bv1, Ws1, bs1, We1,
                                            Q, K, V, S, qWe, N_);
    agg_kernel<<<2048, 256, 0, stream>>>(Q, K, V, S, qWe, We1, row_ptr, csr_src, csr_ea,
                                         h, N_, E_, 1);
    // Layer 2
    node_transform<<<512, 256, 0, stream>>>(h, Wq2, bq2, Wk2, bk2, Wv2, bv2, Ws2, bs2, We2,
                                            Q, K, V, S, qWe, N_);
    agg_kernel<<<2048, 256, 0, stream>>>(Q, K, V, S, qWe, We2, row_ptr, csr_src, csr_ea,
                                         (float*)d_out, N_, E_, 0);
}

// Round 5
// 462.688 us; speedup vs baseline: 2.4658x; 2.4658x over previous
//
#include <hip/hip_runtime.h>
#include <hip/hip_bf16.h>

// ---------------------------------------------------------------------------
// CSR build: histogram of dst, exclusive scan, scatter (src, edge_attr).
// edge_index arrives as int32 (harness converts int64 -> int32), shape [2,E].
// All indices defensively clamped so a bad buffer can never fault the GPU.
// ---------------------------------------------------------------------------
__device__ __forceinline__ int clampi(int v, int lo, int hi) {
    return v < lo ? lo : (v > hi ? hi : v);
}

__global__ void hist_kernel(const int* __restrict__ ei, int* __restrict__ count,
                            int E, int n) {
    int j = blockIdx.x * blockDim.x + threadIdx.x;
    if (j < E) {
        int d = clampi(ei[E + j], 0, n - 1);
        atomicAdd(&count[d], 1);
    }
}

__global__ void scan_exclusive(const int* __restrict__ count, int* __restrict__ row_ptr,
                               int* __restrict__ cursor, int n) {
    __shared__ int wsum[16];
    int tid = threadIdx.x;            // blockDim.x == 1024 (16 waves)
    int lane = tid & 63, wv = tid >> 6;
    int carry = 0;
    for (int base = 0; base < n; base += 1024) {
        int i = base + tid;
        int v = (i < n) ? count[i] : 0;
        int sv = v;
        #pragma unroll
        for (int off = 1; off < 64; off <<= 1) {
            int t = __shfl_up(sv, off, 64);
            if (lane >= off) sv += t;
        }
        if (lane == 63) wsum[wv] = sv;
        __syncthreads();
        if (tid < 16) {
            int ws = wsum[tid];
            #pragma unroll
            for (int off = 1; off < 16; off <<= 1) {
                int t = __shfl_up(ws, off, 64);
                if (tid >= off) ws += t;
            }
            wsum[tid] = ws;
        }
        __syncthreads();
        int addv = carry + (wv ? wsum[wv - 1] : 0);
        if (i < n) {
            int ex = addv + sv - v;
            row_ptr[i] = ex;
            cursor[i] = ex;
        }
        carry += wsum[15];
        __syncthreads();
    }
    if (tid == 0) row_ptr[n] = carry;
}

__global__ void scatter_kernel(const int* __restrict__ ei, const float* __restrict__ ea,
                               int* __restrict__ cursor, int* __restrict__ csr_src,
                               float* __restrict__ csr_ea, int E, int n) {
    int j = blockIdx.x * blockDim.x + threadIdx.x;
    if (j < E) {
        int d = clampi(ei[E + j], 0, n - 1);
        int pos = atomicAdd(&cursor[d], 1);
        if (pos >= 0 && pos < E) {
            csr_src[pos] = clampi(ei[j], 0, n - 1);
            csr_ea[pos] = ea[j];
        }
    }
}

// ---------------------------------------------------------------------------
// Node transform, register-light split version.
// Even blocks compute {Q,K} (+ qWe = Q.We); odd blocks compute {V,S}.
// Weights for the two target matrices interleaved as float2 in 32 KiB LDS.
// Lane l holds x[row][l]; the k-loop broadcasts x[row][k] via __shfl
// (v_readlane -> SGPR operand), so no per-row x register tiles.
// R=8 rows per wave: 24 accumulator/input regs, ~64 VGPR total.
// ---------------------------------------------------------------------------
#define NT_GRID 1568   // must be even; 784 blocks per half = 3136 waves per half

__global__ __launch_bounds__(256) void node_transform(
    const float* __restrict__ xin,
    const float* __restrict__ Wq, const float* __restrict__ bq,
    const float* __restrict__ Wk, const float* __restrict__ bk,
    const float* __restrict__ Wv, const float* __restrict__ bv,
    const float* __restrict__ Ws, const float* __restrict__ bs,
    const float* __restrict__ We,
    float* __restrict__ Q, float* __restrict__ K, float* __restrict__ V,
    float* __restrict__ S, float* __restrict__ qWe, int n)
{
    __shared__ float2 w2[64 * 64];   // 32 KiB
    const int half = blockIdx.x & 1;          // 0 -> {Q,K}, 1 -> {V,S}
    const float* __restrict__ A0 = half ? Wv : Wq;
    const float* __restrict__ A1 = half ? Ws : Wk;
    for (int idx = threadIdx.x; idx < 4096; idx += blockDim.x)
        w2[idx] = make_float2(A0[idx], A1[idx]);
    __syncthreads();

    const int lane = threadIdx.x & 63;
    const int wid  = (blockIdx.x >> 1) * 4 + (threadIdx.x >> 6);
    const int nw   = (gridDim.x >> 1) * 4;

    const float b0 = (half ? bv : bq)[lane];
    const float b1 = (half ? bs : bk)[lane];
    const float we_d = We[lane];
    float* __restrict__ O0 = half ? V : Q;
    float* __restrict__ O1 = half ? S : K;

    const int R = 8;
    for (int r0 = wid * R; r0 < n; r0 += nw * R) {
        float xr[R], a0[R], a1[R];
        #pragma unroll
        for (int r = 0; r < R; ++r) {
            int rr = r0 + r; if (rr >= n) rr = n - 1;
            xr[r] = xin[(size_t)rr * 64 + lane];
            a0[r] = b0; a1[r] = b1;
        }
        #pragma unroll 16
        for (int k = 0; k < 64; ++k) {
            float2 wv = w2[k * 64 + lane];
            #pragma unroll
            for (int r = 0; r < R; ++r) {
                float xs = __shfl(xr[r], k, 64);
                a0[r] = fmaf(xs, wv.x, a0[r]);
                a1[r] = fmaf(xs, wv.y, a1[r]);
            }
        }
        #pragma unroll
        for (int r = 0; r < R; ++r) {
            int rr = r0 + r;
            if (rr >= n) break;
            size_t o = (size_t)rr * 64 + lane;
            O0[o] = a0[r];
            O1[o] = a1[r];
            if (!half) {
                float part = a0[r] * we_d;
                part += __shfl_xor(part, 1);
                part += __shfl_xor(part, 2);
                part += __shfl_xor(part, 4);
                part += __shfl_xor(part, 8);
                part += __shfl_xor(part, 16);
                part += __shfl_xor(part, 32);
                if (lane == 0) qWe[rr] = part;
            }
        }
    }
}

// ---------------------------------------------------------------------------
// Aggregation: one wave per dst node. 4 groups x 16 lanes; each group handles
// one edge per iteration; lane q16 holds quarter-row float4 of K/V rows.
// score = (Q[dst].K[src] + ea*qWe[dst]) / 8 ; softmax w/o max-subtraction
// (scores are O(1): softmax is shift-invariant, no overflow risk).
// out = sum(p * (V[src] + ea*We)) / sum(p) + S[dst]  (+ optional relu).
// ---------------------------------------------------------------------------
__global__ __launch_bounds__(256) void agg_kernel(
    const float* __restrict__ Q, const float* __restrict__ Km, const float* __restrict__ Vm,
    const float* __restrict__ S, const float* __restrict__ qWe, const float* __restrict__ We,
    const int* __restrict__ row_ptr, const int* __restrict__ csr_src,
    const float* __restrict__ csr_ea, float* __restrict__ out, int n, int E, int do_relu)
{
    int lane = threadIdx.x & 63;
    int g = lane >> 4;        // edge slot within iteration
    int q16 = lane & 15;      // quarter-row index
    int wid = (blockIdx.x * blockDim.x + threadIdx.x) >> 6;
    int nw  = (gridDim.x * blockDim.x) >> 6;
    float4 we4 = ((const float4*)We)[q16];

    for (int i = wid; i < n; i += nw) {
        int beg = clampi(row_ptr[i], 0, E);
        int end = clampi(row_ptr[i + 1], beg, E);
        float4 qv = ((const float4*)(Q + (size_t)i * 64))[q16];
        float qwe = qWe[i] * 0.125f;
        float4 acc = make_float4(0.f, 0.f, 0.f, 0.f);
        float ssum = 0.f;

        for (int e0 = beg; e0 < end; e0 += 4) {
            int eidx = e0 + g;
            bool valid = (eidx < end);
            int idx = valid ? eidx : beg;
            int sp = clampi(csr_src[idx], 0, n - 1);
            float ea = csr_ea[idx];
            float4 kv = ((const float4*)(Km + (size_t)sp * 64))[q16];
            float part = qv.x * kv.x + qv.y * kv.y + qv.z * kv.z + qv.w * kv.w;
            part += __shfl_xor(part, 1);
            part += __shfl_xor(part, 2);
            part += __shfl_xor(part, 4);
            part += __shfl_xor(part, 8);
            float score = part * 0.125f + ea * qwe;
            float p = valid ? __expf(score) : 0.f;
            ssum += p;
            float4 vv = ((const float4*)(Vm + (size_t)sp * 64))[q16];
            acc.x += p * (vv.x + ea * we4.x);
            acc.y += p * (vv.y + ea * we4.y);
            acc.z += p * (vv.z + ea * we4.z);
            acc.w += p * (vv.w + ea * we4.w);
        }

        // combine the 4 groups (lanes with equal q16 exchange via xor 16,32)
        ssum += __shfl_xor(ssum, 16); ssum += __shfl_xor(ssum, 32);
        acc.x += __shfl_xor(acc.x, 16); acc.x += __shfl_xor(acc.x, 32);
        acc.y += __shfl_xor(acc.y, 16); acc.y += __shfl_xor(acc.y, 32);
        acc.z += __shfl_xor(acc.z, 16); acc.z += __shfl_xor(acc.z, 32);
        acc.w += __shfl_xor(acc.w, 16); acc.w += __shfl_xor(acc.w, 32);

        float inv = (ssum > 0.f) ? 1.f / ssum : 0.f;
        float4 sr = ((const float4*)(S + (size_t)i * 64))[q16];
        float4 o;
        o.x = acc.x * inv + sr.x;
        o.y = acc.y * inv + sr.y;
        o.z = acc.z * inv + sr.z;
        o.w = acc.w * inv + sr.w;
        if (do_relu) {
            o.x = fmaxf(o.x, 0.f); o.y = fmaxf(o.y, 0.f);
            o.z = fmaxf(o.z, 0.f); o.w = fmaxf(o.w, 0.f);
        }
        if (g == 0) ((float4*)(out + (size_t)i * 64))[q16] = o;
    }
}

// ---------------------------------------------------------------------------
extern "C" void kernel_launch(void* const* d_in, const int* in_sizes, int n_in,
                              void* d_out, int out_size, void* d_ws, size_t ws_size,
                              hipStream_t stream) {
    const float* x   = (const float*)d_in[0];
    const int*   ei  = (const int*)d_in[1];     // int32 on device (harness converts)
    const float* ea  = (const float*)d_in[2];
    const float *Wq1 = (const float*)d_in[3],  *bq1 = (const float*)d_in[4];
    const float *Wk1 = (const float*)d_in[5],  *bk1 = (const float*)d_in[6];
    const float *Wv1 = (const float*)d_in[7],  *bv1 = (const float*)d_in[8];
    const float *We1 = (const float*)d_in[9];
    const float *Ws1 = (const float*)d_in[10], *bs1 = (const float*)d_in[11];
    const float *Wq2 = (const float*)d_in[12], *bq2 = (const float*)d_in[13];
    const float *Wk2 = (const float*)d_in[14], *bk2 = (const float*)d_in[15];
    const float *Wv2 = (const float*)d_in[16], *bv2 = (const float*)d_in[17];
    const float *We2 = (const float*)d_in[18];
    const float *Ws2 = (const float*)d_in[19], *bs2 = (const float*)d_in[20];

    const int N_ = in_sizes[0] / 64;   // 50000
    const int E_ = in_sizes[2];        // 800000

    // carve workspace (256B-aligned)
    char* wsb = (char*)d_ws;
    size_t off = 0;
    auto carve = [&](size_t bytes) -> void* {
        void* p = (void*)(wsb + off);
        off += (bytes + 255) & ~(size_t)255;
        return p;
    };
    float* Q    = (float*)carve((size_t)N_ * 64 * 4);
    float* K    = (float*)carve((size_t)N_ * 64 * 4);
    float* V    = (float*)carve((size_t)N_ * 64 * 4);
    float* S    = (float*)carve((size_t)N_ * 64 * 4);
    float* h    = (float*)carve((size_t)N_ * 64 * 4);
    float* qWe  = (float*)carve((size_t)N_ * 4);
    int*   count   = (int*)carve((size_t)N_ * 4);
    int*   row_ptr = (int*)carve((size_t)(N_ + 1) * 4);
    int*   cursor  = (int*)carve((size_t)N_ * 4);
    int*   csr_src = (int*)carve((size_t)E_ * 4);
    float* csr_ea  = (float*)carve((size_t)E_ * 4);
    (void)ws_size; (void)n_in; (void)out_size;

    // CSR build (shared by both layers)
    hipMemsetAsync(count, 0, (size_t)N_ * 4, stream);
    int eb = (E_ + 255) / 256;
    hist_kernel<<<eb, 256, 0, stream>>>(ei, count, E_, N_);
    scan_exclusive<<<1, 1024, 0, stream>>>(count, row_ptr, cursor, N_);
    scatter_kernel<<<eb, 256, 0, stream>>>(ei, ea, cursor, csr_src, csr_ea, E_, N_);

    // Layer 1
    node_transform<<<NT_GRID, 256, 0, stream>>>(x, Wq1, bq1, Wk1, bk1, Wv1, bv1, Ws1, bs1, We1,
                                                Q, K, V, S, qWe, N_);
    agg_kernel<<<2048, 256, 0, stream>>>(Q, K, V, S, qWe, We1, row_ptr, csr_src, csr_ea,
                                         h, N_, E_, 1);
    // Layer 2
    node_transform<<<NT_GRID, 256, 0, stream>>>(h, Wq2, bq2, Wk2, bk2, Wv2, bv2, Ws2, bs2, We2,
                                                Q, K, V, S, qWe, N_);
    agg_kernel<<<2048, 256, 0, stream>>>(Q, K, V, S, qWe, We2, row_ptr, csr_src, csr_ea,
                                         (float*)d_out, N_, E_, 0);
}

// Round 6
// 293.224 us; speedup vs baseline: 3.8909x; 1.5779x over previous
//
#include <hip/hip_runtime.h>
#include <hip/hip_bf16.h>

typedef short bshort8 __attribute__((ext_vector_type(8)));
typedef float f32x4 __attribute__((ext_vector_type(4)));

__device__ __forceinline__ int clampi(int v, int lo, int hi) {
    return v < lo ? lo : (v > hi ? hi : v);
}
__device__ __forceinline__ ushort f2bf(float f) {           // RNE f32 -> bf16 bits
    uint u = __float_as_uint(f);
    return (ushort)((u + 0x7FFFu + ((u >> 16) & 1u)) >> 16);
}
__device__ __forceinline__ float bf2f(ushort b) { return __uint_as_float(((uint)b) << 16); }

// ---------------------------------------------------------------------------
// CSR build: histogram of dst, exclusive scan, scatter {src, ea} as int2.
// edge_index arrives as int32, shape [2,E]. Indices clamped: never fault.
// ---------------------------------------------------------------------------
__global__ void hist_kernel(const int* __restrict__ ei, int* __restrict__ count,
                            int E, int n) {
    int j = blockIdx.x * blockDim.x + threadIdx.x;
    if (j < E) {
        int d = clampi(ei[E + j], 0, n - 1);
        atomicAdd(&count[d], 1);
    }
}

__global__ void scan_exclusive(const int* __restrict__ count, int* __restrict__ row_ptr,
                               int* __restrict__ cursor, int n) {
    __shared__ int wsum[16];
    int tid = threadIdx.x;            // blockDim.x == 1024 (16 waves)
    int lane = tid & 63, wv = tid >> 6;
    int carry = 0;
    for (int base = 0; base < n; base += 1024) {
        int i = base + tid;
        int v = (i < n) ? count[i] : 0;
        int sv = v;
        #pragma unroll
        for (int off = 1; off < 64; off <<= 1) {
            int t = __shfl_up(sv, off, 64);
            if (lane >= off) sv += t;
        }
        if (lane == 63) wsum[wv] = sv;
        __syncthreads();
        if (tid < 16) {
            int ws = wsum[tid];
            #pragma unroll
            for (int off = 1; off < 16; off <<= 1) {
                int t = __shfl_up(ws, off, 64);
                if (tid >= off) ws += t;
            }
            wsum[tid] = ws;
        }
        __syncthreads();
        int addv = carry + (wv ? wsum[wv - 1] : 0);
        if (i < n) {
            int ex = addv + sv - v;
            row_ptr[i] = ex;
            cursor[i] = ex;
        }
        carry += wsum[15];
        __syncthreads();
    }
    if (tid == 0) row_ptr[n] = carry;
}

__global__ void scatter_kernel(const int* __restrict__ ei, const float* __restrict__ ea,
                               int* __restrict__ cursor, int2* __restrict__ cse,
                               int E, int n) {
    int j = blockIdx.x * blockDim.x + threadIdx.x;
    if (j < E) {
        int d = clampi(ei[E + j], 0, n - 1);
        int pos = atomicAdd(&cursor[d], 1);
        if (pos >= 0 && pos < E)
            cse[pos] = make_int2(clampi(ei[j], 0, n - 1), __float_as_int(ea[j]));
    }
}

// ---------------------------------------------------------------------------
// f32 -> bf16 bulk convert (x only; h is produced in bf16 by agg layer 1)
// ---------------------------------------------------------------------------
__global__ void cvt_bf16_kernel(const float* __restrict__ in, ushort* __restrict__ out, int n4) {
    int i = blockIdx.x * blockDim.x + threadIdx.x;
    int stride = gridDim.x * blockDim.x;
    for (; i < n4; i += stride) {
        float4 v = ((const float4*)in)[i];
        ushort4 o;
        o.x = f2bf(v.x); o.y = f2bf(v.y); o.z = f2bf(v.z); o.w = f2bf(v.w);
        ((ushort4*)out)[i] = o;
    }
}

// ---------------------------------------------------------------------------
// Pack the 4 weight matrices into per-lane MFMA B-fragments (bf16).
// Fragment layout (mfma_f32_16x16x32_bf16): elem i of lane l holds
// B[k][col] with col = 16*(t&3) + (l&15), k = 32*h + 16*(i>>2) + 4*(l>>4) + (i&3).
// Bpack index: ((t*2+h)*64 + lane)*8 + i.  t=0..15 spans {Q,K,V,S} x 4 col-tiles.
// ---------------------------------------------------------------------------
__global__ void pack_weights(const float* __restrict__ Wq, const float* __restrict__ Wk,
                             const float* __restrict__ Wv, const float* __restrict__ Ws,
                             ushort* __restrict__ Bpack) {
    int tid = blockIdx.x * blockDim.x + threadIdx.x;   // 0..2047
    if (tid >= 2048) return;
    int lane = tid & 63;
    int th = tid >> 6;                 // t*2 + h
    int h = th & 1, t = th >> 1;
    const float* W = (t < 4) ? Wq : (t < 8) ? Wk : (t < 12) ? Wv : Ws;
    int col = ((t & 3) << 4) + (lane & 15);
    int g = lane >> 4;
    ushort tmp[8];
    #pragma unroll
    for (int i = 0; i < 8; ++i) {
        int k = 32 * h + 16 * (i >> 2) + 4 * g + (i & 3);
        tmp[i] = f2bf(W[k * 64 + col]);
    }
    #pragma unroll
    for (int i = 0; i < 8; ++i) Bpack[tid * 8 + i] = tmp[i];
}

// ---------------------------------------------------------------------------
// Node transform via MFMA: one wave computes a 16-row x 256-col tile
// (Q|K|V|S, 64 cols each) with 32 mfma_f32_16x16x32_bf16.
// Outputs: Q f32, K bf16, V bf16, S f32, qWe = Q . We (f32).
// ---------------------------------------------------------------------------
__global__ __launch_bounds__(256) void node_transform_mfma(
    const ushort* __restrict__ xb, const ushort* __restrict__ Bpack,
    const float* __restrict__ We,
    float* __restrict__ Q, ushort* __restrict__ Kb, ushort* __restrict__ Vb,
    float* __restrict__ S, float* __restrict__ qWe, int n)
{
    __shared__ bshort8 Blds[2048];    // 32 KiB
    {
        const bshort8* gB = (const bshort8*)Bpack;
        for (int i = threadIdx.x; i < 2048; i += 256) Blds[i] = gB[i];
    }
    __syncthreads();

    int lane = threadIdx.x & 63;
    int wv = threadIdx.x >> 6;
    int tile = blockIdx.x * 4 + wv;
    int ntiles = (n + 15) >> 4;
    if (tile >= ntiles) return;
    int r0 = tile << 4;
    int c = lane & 15, g = lane >> 4;

    int arow = r0 + c; if (arow >= n) arow = n - 1;
    const ushort* xr = xb + (size_t)arow * 64 + 4 * g;
    union { ushort4 u[2]; bshort8 v; } A0, A1;
    A0.u[0] = *(const ushort4*)(xr);        // k = 4g..4g+3
    A0.u[1] = *(const ushort4*)(xr + 16);   // k = 16+4g..
    A1.u[0] = *(const ushort4*)(xr + 32);
    A1.u[1] = *(const ushort4*)(xr + 48);

    f32x4 acc[16];
    #pragma unroll
    for (int t = 0; t < 16; ++t) acc[t] = (f32x4){0.f, 0.f, 0.f, 0.f};
    #pragma unroll
    for (int t = 0; t < 16; ++t) {
        acc[t] = __builtin_amdgcn_mfma_f32_16x16x32_bf16(A0.v, Blds[(2 * t) * 64 + lane], acc[t], 0, 0, 0);
        acc[t] = __builtin_amdgcn_mfma_f32_16x16x32_bf16(A1.v, Blds[(2 * t + 1) * 64 + lane], acc[t], 0, 0, 0);
    }

    // qWe[row] = dot(Q[row], We); lane holds Q[4g+j][16t+c] in acc[t][j], t<4
    float we0 = We[c], we1 = We[16 + c], we2 = We[32 + c], we3 = We[48 + c];
    #pragma unroll
    for (int j = 0; j < 4; ++j) {
        float part = acc[0][j] * we0 + acc[1][j] * we1 + acc[2][j] * we2 + acc[3][j] * we3;
        part += __shfl_xor(part, 1);
        part += __shfl_xor(part, 2);
        part += __shfl_xor(part, 4);
        part += __shfl_xor(part, 8);
        int orow = r0 + 4 * g + j;
        if (c == 0 && orow < n) qWe[orow] = part;
    }

    #pragma unroll
    for (int tt = 0; tt < 4; ++tt) {
        #pragma unroll
        for (int j = 0; j < 4; ++j) {
            int orow = r0 + 4 * g + j;
            if (orow >= n) continue;
            size_t o = (size_t)orow * 64 + 16 * tt + c;
            Q[o]  = acc[tt][j];
            Kb[o] = f2bf(acc[4 + tt][j]);
            Vb[o] = f2bf(acc[8 + tt][j]);
            S[o]  = acc[12 + tt][j];
        }
    }
}

// ---------------------------------------------------------------------------
// Aggregation: one wave per dst node; 4 groups x 16 lanes, 1 edge/group/iter.
// K,V rows are bf16 (8B/lane gathers). score = (Q[dst].K[src] + ea*qWe)/8.
// L1: out = bf16 h with relu; else: f32 d_out.
// ---------------------------------------------------------------------------
template<int L1>
__global__ __launch_bounds__(256) void agg_kernel(
    const float* __restrict__ Q, const ushort* __restrict__ Kb, const ushort* __restrict__ Vb,
    const float* __restrict__ S, const float* __restrict__ qWe, const float* __restrict__ We,
    const int* __restrict__ row_ptr, const int2* __restrict__ cse,
    void* __restrict__ outp, int n, int E)
{
    int lane = threadIdx.x & 63;
    int g = lane >> 4;        // edge slot within iteration
    int q16 = lane & 15;      // quarter-row index (cols 4q16..4q16+3)
    int wid = (blockIdx.x * blockDim.x + threadIdx.x) >> 6;
    int nw  = (gridDim.x * blockDim.x) >> 6;
    float4 we4 = ((const float4*)We)[q16];

    for (int i = wid; i < n; i += nw) {
        int beg = clampi(row_ptr[i], 0, E);
        int end = clampi(row_ptr[i + 1], beg, E);
        float4 qv = ((const float4*)(Q + (size_t)i * 64))[q16];
        float qwe = qWe[i] * 0.125f;
        float4 acc = make_float4(0.f, 0.f, 0.f, 0.f);
        float ssum = 0.f;

        for (int e0 = beg; e0 < end; e0 += 4) {
            int eidx = e0 + g;
            bool valid = (eidx < end);
            int idx = valid ? eidx : beg;
            int2 e = cse[idx];
            int sp = clampi(e.x, 0, n - 1);
            float ea = __int_as_float(e.y);
            ushort4 k4 = *(const ushort4*)(Kb + (size_t)sp * 64 + 4 * q16);
            float part = qv.x * bf2f(k4.x) + qv.y * bf2f(k4.y)
                       + qv.z * bf2f(k4.z) + qv.w * bf2f(k4.w);
            part += __shfl_xor(part, 1);
            part += __shfl_xor(part, 2);
            part += __shfl_xor(part, 4);
            part += __shfl_xor(part, 8);
            float score = part * 0.125f + ea * qwe;
            float p = valid ? __expf(score) : 0.f;
            ssum += p;
            ushort4 v4 = *(const ushort4*)(Vb + (size_t)sp * 64 + 4 * q16);
            acc.x += p * (bf2f(v4.x) + ea * we4.x);
            acc.y += p * (bf2f(v4.y) + ea * we4.y);
            acc.z += p * (bf2f(v4.z) + ea * we4.z);
            acc.w += p * (bf2f(v4.w) + ea * we4.w);
        }

        ssum += __shfl_xor(ssum, 16); ssum += __shfl_xor(ssum, 32);
        acc.x += __shfl_xor(acc.x, 16); acc.x += __shfl_xor(acc.x, 32);
        acc.y += __shfl_xor(acc.y, 16); acc.y += __shfl_xor(acc.y, 32);
        acc.z += __shfl_xor(acc.z, 16); acc.z += __shfl_xor(acc.z, 32);
        acc.w += __shfl_xor(acc.w, 16); acc.w += __shfl_xor(acc.w, 32);

        float inv = (ssum > 0.f) ? 1.f / ssum : 0.f;
        float4 sr = ((const float4*)(S + (size_t)i * 64))[q16];
        float ox = acc.x * inv + sr.x;
        float oy = acc.y * inv + sr.y;
        float oz = acc.z * inv + sr.z;
        float ow = acc.w * inv + sr.w;
        if (L1) {
            ox = fmaxf(ox, 0.f); oy = fmaxf(oy, 0.f);
            oz = fmaxf(oz, 0.f); ow = fmaxf(ow, 0.f);
            if (g == 0) {
                ushort4 o;
                o.x = f2bf(ox); o.y = f2bf(oy); o.z = f2bf(oz); o.w = f2bf(ow);
                *(ushort4*)((ushort*)outp + (size_t)i * 64 + 4 * q16) = o;
            }
        } else {
            if (g == 0)
                ((float4*)((float*)outp + (size_t)i * 64))[q16] = make_float4(ox, oy, oz, ow);
        }
    }
}

// ---------------------------------------------------------------------------
extern "C" void kernel_launch(void* const* d_in, const int* in_sizes, int n_in,
                              void* d_out, int out_size, void* d_ws, size_t ws_size,
                              hipStream_t stream) {
    const float* x   = (const float*)d_in[0];
    const int*   ei  = (const int*)d_in[1];     // int32 on device
    const float* ea  = (const float*)d_in[2];
    const float *Wq1 = (const float*)d_in[3],  *bq1 = (const float*)d_in[4];
    const float *Wk1 = (const float*)d_in[5],  *bk1 = (const float*)d_in[6];
    const float *Wv1 = (const float*)d_in[7],  *bv1 = (const float*)d_in[8];
    const float *We1 = (const float*)d_in[9];
    const float *Ws1 = (const float*)d_in[10], *bs1 = (const float*)d_in[11];
    const float *Wq2 = (const float*)d_in[12], *bq2 = (const float*)d_in[13];
    const float *Wk2 = (const float*)d_in[14], *bk2 = (const float*)d_in[15];
    const float *Wv2 = (const float*)d_in[16], *bv2 = (const float*)d_in[17];
    const float *We2 = (const float*)d_in[18];
    const float *Ws2 = (const float*)d_in[19], *bs2 = (const float*)d_in[20];
    (void)bq1; (void)bk1; (void)bv1; (void)bs1;   // biases folded below via pack? no:
    // NOTE: biases are NOT folded into MFMA (K=64 exactly); we add them via We-style
    // constant rows? -- they must be added. See bias handling below.

    const int N_ = in_sizes[0] / 64;   // 50000
    const int E_ = in_sizes[2];        // 800000

    char* wsb = (char*)d_ws;
    size_t off = 0;
    auto carve = [&](size_t bytes) -> void* {
        void* p = (void*)(wsb + off);
        off += (bytes + 255) & ~(size_t)255;
        return p;
    };
    float*  Q    = (float*)carve((size_t)N_ * 64 * 4);
    float*  S    = (float*)carve((size_t)N_ * 64 * 4);
    ushort* Kb   = (ushort*)carve((size_t)N_ * 64 * 2);
    ushort* Vb   = (ushort*)carve((size_t)N_ * 64 * 2);
    ushort* xbuf = (ushort*)carve((size_t)N_ * 64 * 2);
    ushort* hb   = (ushort*)carve((size_t)N_ * 64 * 2);
    float*  qWe  = (float*)carve((size_t)N_ * 4);
    int*    count   = (int*)carve((size_t)N_ * 4);
    int*    row_ptr = (int*)carve((size_t)(N_ + 1) * 4);
    int*    cursor  = (int*)carve((size_t)N_ * 4);
    int2*   cse     = (int2*)carve((size_t)E_ * 8);
    ushort* Bp1     = (ushort*)carve(2048 * 8 * 2);
    ushort* Bp2     = (ushort*)carve(2048 * 8 * 2);
    float*  bias1   = (float*)carve(4 * 64 * 4);
    float*  bias2   = (float*)carve(4 * 64 * 4);
    (void)ws_size; (void)n_in; (void)out_size; (void)bias1; (void)bias2;

    hipMemsetAsync(count, 0, (size_t)N_ * 4, stream);
    cvt_bf16_kernel<<<1024, 256, 0, stream>>>(x, xbuf, N_ * 16);
    pack_weights<<<8, 256, 0, stream>>>(Wq1, Wk1, Wv1, Ws1, Bp1);
    pack_weights<<<8, 256, 0, stream>>>(Wq2, Wk2, Wv2, Ws2, Bp2);

    int eb = (E_ + 255) / 256;
    hist_kernel<<<eb, 256, 0, stream>>>(ei, count, E_, N_);
    scan_exclusive<<<1, 1024, 0, stream>>>(count, row_ptr, cursor, N_);
    scatter_kernel<<<eb, 256, 0, stream>>>(ei, ea, cursor, cse, E_, N_);

    int ntb = ((N_ + 15) / 16 + 3) / 4;    // blocks of 4 wave-tiles

    // ---- bias handling: add biases as a K-augmentation is impossible (K=64 used);
    // instead biases are added in a tiny epilogue pass fused into agg via S/Q/K/V:
    // We fold bq into Q, bk into K, bv into V, bs into S with a small kernel.
    // Simpler: the MFMA kernel writes unbiased outputs; bias_fix adds them.
    // (bias_fix is memory-cheap: one pass over 4 x N x 64.)
    node_transform_mfma<<<ntb, 256, 0, stream>>>(xbuf, Bp1, We1, Q, Kb, Vb, S, qWe, N_);
    {
        // fused bias add over Q,K,V,S + qWe correction
        struct BiasArgs {};
        extern __global__ void bias_add(float*, ushort*, ushort*, float*, float*,
                                        const float*, const float*, const float*,
                                        const float*, const float*, int);
        bias_add<<<1024, 256, 0, stream>>>(Q, Kb, Vb, S, qWe, bq1, bk1, bv1, bs1, We1, N_);
    }
    agg_kernel<1><<<2048, 256, 0, stream>>>(Q, Kb, Vb, S, qWe, We1, row_ptr, cse, hb, N_, E_);

    node_transform_mfma<<<ntb, 256, 0, stream>>>(hb, Bp2, We2, Q, Kb, Vb, S, qWe, N_);
    {
        extern __global__ void bias_add(float*, ushort*, ushort*, float*, float*,
                                        const float*, const float*, const float*,
                                        const float*, const float*, int);
        bias_add<<<1024, 256, 0, stream>>>(Q, Kb, Vb, S, qWe, bq2, bk2, bv2, bs2, We2, N_);
    }
    agg_kernel<0><<<2048, 256, 0, stream>>>(Q, Kb, Vb, S, qWe, We2, row_ptr, cse, d_out, N_, E_);
}

// Bias epilogue: Q += bq, K += bk, V += bv, S += bs (bf16 re-round for K,V),
// qWe += dot(bq, We). One wave per 4 rows.
__global__ __launch_bounds__(256) void bias_add(
    float* __restrict__ Q, ushort* __restrict__ Kb, ushort* __restrict__ Vb,
    float* __restrict__ S, float* __restrict__ qWe,
    const float* __restrict__ bq, const float* __restrict__ bk,
    const float* __restrict__ bv, const float* __restrict__ bs,
    const float* __restrict__ We, int n)
{
    int lane = threadIdx.x & 63;
    int wid = (blockIdx.x * blockDim.x + threadIdx.x) >> 6;
    int nw  = (gridDim.x * blockDim.x) >> 6;
    float vbq = bq[lane], vbk = bk[lane], vbv = bv[lane], vbs = bs[lane];
    // dot(bq, We) (same on every wave; cheap)
    float bqwe = vbq * We[lane];
    bqwe += __shfl_xor(bqwe, 1);  bqwe += __shfl_xor(bqwe, 2);
    bqwe += __shfl_xor(bqwe, 4);  bqwe += __shfl_xor(bqwe, 8);
    bqwe += __shfl_xor(bqwe, 16); bqwe += __shfl_xor(bqwe, 32);

    for (int r = wid; r < n; r += nw) {
        size_t o = (size_t)r * 64 + lane;
        Q[o] += vbq;
        Kb[o] = f2bf(bf2f(Kb[o]) + vbk);
        Vb[o] = f2bf(bf2f(Vb[o]) + vbv);
        S[o] += vbs;
        if (lane == 0) qWe[r] += bqwe;
    }
}

// Round 7
// 271.202 us; speedup vs baseline: 4.2068x; 1.0812x over previous
//
#include <hip/hip_runtime.h>
#include <hip/hip_bf16.h>

typedef short bshort8 __attribute__((ext_vector_type(8)));
typedef float f32x4 __attribute__((ext_vector_type(4)));
typedef unsigned short ushort8v __attribute__((ext_vector_type(8)));

__device__ __forceinline__ int clampi(int v, int lo, int hi) {
    return v < lo ? lo : (v > hi ? hi : v);
}
__device__ __forceinline__ ushort f2bf(float f) {           // RNE f32 -> bf16 bits
    uint u = __float_as_uint(f);
    return (ushort)((u + 0x7FFFu + ((u >> 16) & 1u)) >> 16);
}
__device__ __forceinline__ float bf2f(ushort b) { return __uint_as_float(((uint)b) << 16); }
__device__ __forceinline__ float xgrp(float v) {            // combine 8 groups of 8
    v += __shfl_xor(v, 8); v += __shfl_xor(v, 16); v += __shfl_xor(v, 32); return v;
}

// ---------------------------------------------------------------------------
// CSR build, XCD-sharded: replica r = blockIdx.x & 7 handles dst range
// [r*n/8, (r+1)*n/8) so all writes/atomics of a CSR region come from one XCD
// (blockIdx % 8 -> XCD round-robin heuristic; correctness never depends on it).
// ---------------------------------------------------------------------------
__global__ void hist_kernel(const int* __restrict__ ei, int* __restrict__ count,
                            int E, int n) {
    int r = blockIdx.x & 7;
    int nb = gridDim.x >> 3, cb = blockIdx.x >> 3;
    int rlo = r * n, rhi = rlo + n;          // compare d*8 against [r*n, (r+1)*n)
    for (int j = cb * 256 + threadIdx.x; j < E; j += nb * 256) {
        int d = clampi(ei[E + j], 0, n - 1);
        int d8 = d << 3;
        if (d8 >= rlo && d8 < rhi) atomicAdd(&count[d], 1);
    }
}

__global__ void scan_exclusive(const int* __restrict__ count, int* __restrict__ row_ptr,
                               int* __restrict__ cursor, int n) {
    __shared__ int wsum[16];
    int tid = threadIdx.x;            // blockDim.x == 1024 (16 waves)
    int lane = tid & 63, wv = tid >> 6;
    int carry = 0;
    for (int base = 0; base < n; base += 1024) {
        int i = base + tid;
        int v = (i < n) ? count[i] : 0;
        int sv = v;
        #pragma unroll
        for (int off = 1; off < 64; off <<= 1) {
            int t = __shfl_up(sv, off, 64);
            if (lane >= off) sv += t;
        }
        if (lane == 63) wsum[wv] = sv;
        __syncthreads();
        if (tid < 16) {
            int ws = wsum[tid];
            #pragma unroll
            for (int off = 1; off < 16; off <<= 1) {
                int t = __shfl_up(ws, off, 64);
                if (tid >= off) ws += t;
            }
            wsum[tid] = ws;
        }
        __syncthreads();
        int addv = carry + (wv ? wsum[wv - 1] : 0);
        if (i < n) {
            int ex = addv + sv - v;
            row_ptr[i] = ex;
            cursor[i] = ex;
        }
        carry += wsum[15];
        __syncthreads();
    }
    if (tid == 0) row_ptr[n] = carry;
}

__global__ void scatter_kernel(const int* __restrict__ ei, const float* __restrict__ ea,
                               int* __restrict__ cursor, int2* __restrict__ cse,
                               int E, int n) {
    int r = blockIdx.x & 7;
    int nb = gridDim.x >> 3, cb = blockIdx.x >> 3;
    int rlo = r * n, rhi = rlo + n;
    for (int j = cb * 256 + threadIdx.x; j < E; j += nb * 256) {
        int d = clampi(ei[E + j], 0, n - 1);
        int d8 = d << 3;
        if (d8 >= rlo && d8 < rhi) {
            int pos = atomicAdd(&cursor[d], 1);
            if (pos >= 0 && pos < E)
                cse[pos] = make_int2(clampi(ei[j], 0, n - 1), __float_as_int(ea[j]));
        }
    }
}

// ---------------------------------------------------------------------------
// Pack both layers' weight matrices into per-lane MFMA B-fragments (bf16).
// Fragment layout (mfma_f32_16x16x32_bf16, empirically validated r6): elem i of
// lane l holds B[k][col], col = 16*(t&3)+(l&15), k = 32*h+16*(i>>2)+4*(l>>4)+(i&3).
// ---------------------------------------------------------------------------
__global__ void pack_weights(const float* __restrict__ Wq1, const float* __restrict__ Wk1,
                             const float* __restrict__ Wv1, const float* __restrict__ Ws1,
                             const float* __restrict__ Wq2, const float* __restrict__ Wk2,
                             const float* __restrict__ Wv2, const float* __restrict__ Ws2,
                             ushort* __restrict__ Bp1, ushort* __restrict__ Bp2) {
    int tid = blockIdx.x * blockDim.x + threadIdx.x;   // 0..4095
    if (tid >= 4096) return;
    int layer = tid >> 11;
    int t2 = tid & 2047;
    int lane = t2 & 63;
    int th = t2 >> 6;                  // t*2 + h
    int h = th & 1, t = th >> 1;
    const float* W = layer ? ((t < 4) ? Wq2 : (t < 8) ? Wk2 : (t < 12) ? Wv2 : Ws2)
                           : ((t < 4) ? Wq1 : (t < 8) ? Wk1 : (t < 12) ? Wv1 : Ws1);
    ushort* Bp = layer ? Bp2 : Bp1;
    int col = ((t & 3) << 4) + (lane & 15);
    int g = lane >> 4;
    #pragma unroll
    for (int i = 0; i < 8; ++i) {
        int k = 32 * h + 16 * (i >> 2) + 4 * g + (i & 3);
        Bp[t2 * 8 + i] = f2bf(W[k * 64 + col]);
    }
}

// ---------------------------------------------------------------------------
// Node transform via MFMA, biases folded into the epilogue.
// One wave computes a 16-row x 256-col tile (Q|K|V|S) with 32 MFMAs.
// Outputs: Q f32, KV interleaved bf16 [row][128] (K=0..63, V=64..127), S f32,
// qWe = (Q+bq).We.  INF32: read f32 input and convert in-register.
// ---------------------------------------------------------------------------
template<bool INF32>
__global__ __launch_bounds__(256) void node_transform_mfma(
    const void* __restrict__ xin, const ushort* __restrict__ Bpack,
    const float* __restrict__ We,
    const float* __restrict__ bq, const float* __restrict__ bk,
    const float* __restrict__ bv, const float* __restrict__ bs,
    float* __restrict__ Q, ushort* __restrict__ KVb,
    float* __restrict__ S, float* __restrict__ qWe, int n)
{
    __shared__ bshort8 Blds[2048];    // 32 KiB
    {
        const bshort8* gB = (const bshort8*)Bpack;
        for (int i = threadIdx.x; i < 2048; i += 256) Blds[i] = gB[i];
    }
    __syncthreads();

    int lane = threadIdx.x & 63;
    int wv = threadIdx.x >> 6;
    int tile = blockIdx.x * 4 + wv;
    int ntiles = (n + 15) >> 4;
    if (tile >= ntiles) return;
    int r0 = tile << 4;
    int c = lane & 15, g = lane >> 4;

    int arow = r0 + c; if (arow >= n) arow = n - 1;
    union { ushort4 u[2]; bshort8 v; } A0, A1;
    if constexpr (INF32) {
        const float* xr = (const float*)xin + (size_t)arow * 64 + 4 * g;
        float4 f0 = *(const float4*)(xr);
        float4 f1 = *(const float4*)(xr + 16);
        float4 f2 = *(const float4*)(xr + 32);
        float4 f3 = *(const float4*)(xr + 48);
        A0.u[0] = make_ushort4(f2bf(f0.x), f2bf(f0.y), f2bf(f0.z), f2bf(f0.w));
        A0.u[1] = make_ushort4(f2bf(f1.x), f2bf(f1.y), f2bf(f1.z), f2bf(f1.w));
        A1.u[0] = make_ushort4(f2bf(f2.x), f2bf(f2.y), f2bf(f2.z), f2bf(f2.w));
        A1.u[1] = make_ushort4(f2bf(f3.x), f2bf(f3.y), f2bf(f3.z), f2bf(f3.w));
    } else {
        const ushort* xr = (const ushort*)xin + (size_t)arow * 64 + 4 * g;
        A0.u[0] = *(const ushort4*)(xr);
        A0.u[1] = *(const ushort4*)(xr + 16);
        A1.u[0] = *(const ushort4*)(xr + 32);
        A1.u[1] = *(const ushort4*)(xr + 48);
    }

    f32x4 acc[16];
    #pragma unroll
    for (int t = 0; t < 16; ++t) acc[t] = (f32x4){0.f, 0.f, 0.f, 0.f};
    #pragma unroll
    for (int t = 0; t < 16; ++t) {
        acc[t] = __builtin_amdgcn_mfma_f32_16x16x32_bf16(A0.v, Blds[(2 * t) * 64 + lane], acc[t], 0, 0, 0);
        acc[t] = __builtin_amdgcn_mfma_f32_16x16x32_bf16(A1.v, Blds[(2 * t + 1) * 64 + lane], acc[t], 0, 0, 0);
    }

    float we_c[4], bq_c[4];
    #pragma unroll
    for (int t = 0; t < 4; ++t) { we_c[t] = We[16 * t + c]; bq_c[t] = bq[16 * t + c]; }
    #pragma unroll
    for (int j = 0; j < 4; ++j) {
        float part = 0.f;
        #pragma unroll
        for (int t = 0; t < 4; ++t) part += (acc[t][j] + bq_c[t]) * we_c[t];
        part += __shfl_xor(part, 1);
        part += __shfl_xor(part, 2);
        part += __shfl_xor(part, 4);
        part += __shfl_xor(part, 8);
        int orow = r0 + 4 * g + j;
        if (c == 0 && orow < n) qWe[orow] = part;
    }

    #pragma unroll
    for (int tt = 0; tt < 4; ++tt) {
        int col = 16 * tt + c;
        float vbk = bk[col], vbv = bv[col], vbs = bs[col];
        #pragma unroll
        for (int j = 0; j < 4; ++j) {
            int orow = r0 + 4 * g + j;
            if (orow >= n) continue;
            size_t o = (size_t)orow * 64 + col;
            Q[o] = acc[tt][j] + bq_c[tt];
            KVb[(size_t)orow * 128 + col]      = f2bf(acc[4 + tt][j] + vbk);
            KVb[(size_t)orow * 128 + 64 + col] = f2bf(acc[8 + tt][j] + vbv);
            S[o] = acc[12 + tt][j] + vbs;
        }
    }
}

// ---------------------------------------------------------------------------
// Aggregation: one wave per dst node; 8 groups x 8 lanes, 8 edges/iter.
// KV rows interleaved bf16: one 16B load per lane per operand.
// score = (Q[dst].K[src] + ea*qWe[dst]) / 8; softmax w/o max-subtraction
// (scores are O(1), softmax shift-invariant). out = agg + S (+relu for L1).
// ---------------------------------------------------------------------------
template<int L1>
__global__ __launch_bounds__(256) void agg_kernel(
    const float* __restrict__ Q, const ushort* __restrict__ KVb,
    const float* __restrict__ S, const float* __restrict__ qWe,
    const float* __restrict__ We, const int* __restrict__ row_ptr,
    const int2* __restrict__ cse, void* __restrict__ outp, int n, int E)
{
    int lane = threadIdx.x & 63;
    int g = lane >> 3, q8 = lane & 7;
    int wid = (blockIdx.x * blockDim.x + threadIdx.x) >> 6;
    int nw  = (gridDim.x * blockDim.x) >> 6;
    float4 weA = ((const float4*)We)[2 * q8];
    float4 weB = ((const float4*)We)[2 * q8 + 1];

    for (int i = wid; i < n; i += nw) {
        int beg = clampi(row_ptr[i], 0, E);
        int end = clampi(row_ptr[i + 1], beg, E);
        const float4* Qrow = (const float4*)(Q + (size_t)i * 64);
        float4 qA = Qrow[2 * q8], qB = Qrow[2 * q8 + 1];
        float qwe = qWe[i] * 0.125f;
        f32x4 aA = {0.f, 0.f, 0.f, 0.f}, aB = {0.f, 0.f, 0.f, 0.f};
        float ssum = 0.f;

        for (int e0 = beg; e0 < end; e0 += 8) {
            int eidx = e0 + g;
            bool valid = (eidx < end);
            int idx = valid ? eidx : beg;
            int2 e = cse[idx];
            int sp = clampi(e.x, 0, n - 1);
            float ea = __int_as_float(e.y);
            const ushort8v* kv = (const ushort8v*)(KVb + (size_t)sp * 128 + 8 * q8);
            ushort8v k8 = kv[0];
            float part = qA.x * bf2f(k8[0]) + qA.y * bf2f(k8[1])
                       + qA.z * bf2f(k8[2]) + qA.w * bf2f(k8[3])
                       + qB.x * bf2f(k8[4]) + qB.y * bf2f(k8[5])
                       + qB.z * bf2f(k8[6]) + qB.w * bf2f(k8[7]);
            part += __shfl_xor(part, 1);
            part += __shfl_xor(part, 2);
            part += __shfl_xor(part, 4);
            float score = part * 0.125f + ea * qwe;
            float p = valid ? __expf(score) : 0.f;
            ssum += p;
            ushort8v v8 = kv[8];          // +64 ushorts: V half of the row
            aA[0] += p * (bf2f(v8[0]) + ea * weA.x);
            aA[1] += p * (bf2f(v8[1]) + ea * weA.y);
            aA[2] += p * (bf2f(v8[2]) + ea * weA.z);
            aA[3] += p * (bf2f(v8[3]) + ea * weA.w);
            aB[0] += p * (bf2f(v8[4]) + ea * weB.x);
            aB[1] += p * (bf2f(v8[5]) + ea * weB.y);
            aB[2] += p * (bf2f(v8[6]) + ea * weB.z);
            aB[3] += p * (bf2f(v8[7]) + ea * weB.w);
        }

        ssum = xgrp(ssum);
        #pragma unroll
        for (int t = 0; t < 4; ++t) { aA[t] = xgrp(aA[t]); aB[t] = xgrp(aB[t]); }
        float inv = (ssum > 0.f) ? 1.f / ssum : 0.f;
        const float4* Srow = (const float4*)(S + (size_t)i * 64);
        float4 sA = Srow[2 * q8], sB = Srow[2 * q8 + 1];
        float o0 = aA[0] * inv + sA.x, o1 = aA[1] * inv + sA.y;
        float o2 = aA[2] * inv + sA.z, o3 = aA[3] * inv + sA.w;
        float o4 = aB[0] * inv + sB.x, o5 = aB[1] * inv + sB.y;
        float o6 = aB[2] * inv + sB.z, o7 = aB[3] * inv + sB.w;
        if (L1) {
            o0 = fmaxf(o0, 0.f); o1 = fmaxf(o1, 0.f); o2 = fmaxf(o2, 0.f); o3 = fmaxf(o3, 0.f);
            o4 = fmaxf(o4, 0.f); o5 = fmaxf(o5, 0.f); o6 = fmaxf(o6, 0.f); o7 = fmaxf(o7, 0.f);
            if (g == 0) {
                union { ushort u[8]; ushort8v v; } ov;
                ov.u[0] = f2bf(o0); ov.u[1] = f2bf(o1); ov.u[2] = f2bf(o2); ov.u[3] = f2bf(o3);
                ov.u[4] = f2bf(o4); ov.u[5] = f2bf(o5); ov.u[6] = f2bf(o6); ov.u[7] = f2bf(o7);
                *(ushort8v*)((ushort*)outp + (size_t)i * 64 + 8 * q8) = ov.v;
            }
        } else {
            if (g == 0) {
                float4* Or = (float4*)((float*)outp + (size_t)i * 64);
                Or[2 * q8]     = make_float4(o0, o1, o2, o3);
                Or[2 * q8 + 1] = make_float4(o4, o5, o6, o7);
            }
        }
    }
}

// ---------------------------------------------------------------------------
extern "C" void kernel_launch(void* const* d_in, const int* in_sizes, int n_in,
                              void* d_out, int out_size, void* d_ws, size_t ws_size,
                              hipStream_t stream) {
    const float* x   = (const float*)d_in[0];
    const int*   ei  = (const int*)d_in[1];     // int32 on device
    const float* ea  = (const float*)d_in[2];
    const float *Wq1 = (const float*)d_in[3],  *bq1 = (const float*)d_in[4];
    const float *Wk1 = (const float*)d_in[5],  *bk1 = (const float*)d_in[6];
    const float *Wv1 = (const float*)d_in[7],  *bv1 = (const float*)d_in[8];
    const float *We1 = (const float*)d_in[9];
    const float *Ws1 = (const float*)d_in[10], *bs1 = (const float*)d_in[11];
    const float *Wq2 = (const float*)d_in[12], *bq2 = (const float*)d_in[13];
    const float *Wk2 = (const float*)d_in[14], *bk2 = (const float*)d_in[15];
    const float *Wv2 = (const float*)d_in[16], *bv2 = (const float*)d_in[17];
    const float *We2 = (const float*)d_in[18];
    const float *Ws2 = (const float*)d_in[19], *bs2 = (const float*)d_in[20];

    const int N_ = in_sizes[0] / 64;   // 50000
    const int E_ = in_sizes[2];        // 800000

    char* wsb = (char*)d_ws;
    size_t off = 0;
    auto carve = [&](size_t bytes) -> void* {
        void* p = (void*)(wsb + off);
        off += (bytes + 255) & ~(size_t)255;
        return p;
    };
    float*  Q    = (float*)carve((size_t)N_ * 64 * 4);
    float*  S    = (float*)carve((size_t)N_ * 64 * 4);
    ushort* KVb  = (ushort*)carve((size_t)N_ * 128 * 2);
    ushort* hb   = (ushort*)carve((size_t)N_ * 64 * 2);
    float*  qWe  = (float*)carve((size_t)N_ * 4);
    int*    count   = (int*)carve((size_t)N_ * 4);
    int*    row_ptr = (int*)carve((size_t)(N_ + 1) * 4);
    int*    cursor  = (int*)carve((size_t)N_ * 4);
    int2*   cse     = (int2*)carve((size_t)E_ * 8);
    ushort* Bp1     = (ushort*)carve(2048 * 8 * 2);
    ushort* Bp2     = (ushort*)carve(2048 * 8 * 2);
    (void)ws_size; (void)n_in; (void)out_size;

    hipMemsetAsync(count, 0, (size_t)N_ * 4, stream);
    pack_weights<<<16, 256, 0, stream>>>(Wq1, Wk1, Wv1, Ws1, Wq2, Wk2, Wv2, Ws2, Bp1, Bp2);

    // CSR build (XCD-sharded histogram + scatter)
    hist_kernel<<<3136, 256, 0, stream>>>(ei, count, E_, N_);
    scan_exclusive<<<1, 1024, 0, stream>>>(count, row_ptr, cursor, N_);
    scatter_kernel<<<3136, 256, 0, stream>>>(ei, ea, cursor, cse, E_, N_);

    int ntb = (((N_ + 15) / 16) + 3) / 4;

    // Layer 1
    node_transform_mfma<true><<<ntb, 256, 0, stream>>>(x, Bp1, We1, bq1, bk1, bv1, bs1,
                                                       Q, KVb, S, qWe, N_);
    agg_kernel<1><<<2048, 256, 0, stream>>>(Q, KVb, S, qWe, We1, row_ptr, cse, hb, N_, E_);
    // Layer 2
    node_transform_mfma<false><<<ntb, 256, 0, stream>>>(hb, Bp2, We2, bq2, bk2, bv2, bs2,
                                                        Q, KVb, S, qWe, N_);
    agg_kernel<0><<<2048, 256, 0, stream>>>(Q, KVb, S, qWe, We2, row_ptr, cse, d_out, N_, E_);
}

// Round 8
// 260.277 us; speedup vs baseline: 4.3834x; 1.0420x over previous
//
#include <hip/hip_runtime.h>
#include <hip/hip_bf16.h>

typedef short bshort8 __attribute__((ext_vector_type(8)));
typedef float f32x4 __attribute__((ext_vector_type(4)));
typedef unsigned short ushort8v __attribute__((ext_vector_type(8)));

__device__ __forceinline__ int clampi(int v, int lo, int hi) {
    return v < lo ? lo : (v > hi ? hi : v);
}
__device__ __forceinline__ ushort f2bf(float f) {           // RNE f32 -> bf16 bits
    uint u = __float_as_uint(f);
    return (ushort)((u + 0x7FFFu + ((u >> 16) & 1u)) >> 16);
}
__device__ __forceinline__ float bf2f(ushort b) { return __uint_as_float(((uint)b) << 16); }
__device__ __forceinline__ float xgrp(float v) {            // combine 8 groups of 8
    v += __shfl_xor(v, 8); v += __shfl_xor(v, 16); v += __shfl_xor(v, 32); return v;
}

// ---------------------------------------------------------------------------
// CSR build. hist: plain device-scope atomics (one coalesced pass).
// ---------------------------------------------------------------------------
__global__ void hist_kernel(const int* __restrict__ ei, int* __restrict__ count,
                            int E, int n) {
    int j = blockIdx.x * blockDim.x + threadIdx.x;
    if (j < E) {
        int d = clampi(ei[E + j], 0, n - 1);
        atomicAdd(&count[d], 1);
    }
}

// Exclusive scan, single block of 1024 threads, 4 elements per thread per pass.
__global__ void scan_exclusive(const int* __restrict__ count, int* __restrict__ row_ptr,
                               int* __restrict__ cursor, int n) {
    __shared__ int wsum[16];
    int tid = threadIdx.x, lane = tid & 63, wv = tid >> 6;
    int carry = 0;
    for (int base = 0; base < n; base += 4096) {
        int i4 = base + tid * 4;
        int v0 = 0, v1 = 0, v2 = 0, v3 = 0;
        if (i4 + 3 < n) {
            int4 t = *(const int4*)(count + i4);
            v0 = t.x; v1 = t.y; v2 = t.z; v3 = t.w;
        } else {
            if (i4     < n) v0 = count[i4];
            if (i4 + 1 < n) v1 = count[i4 + 1];
            if (i4 + 2 < n) v2 = count[i4 + 2];
            if (i4 + 3 < n) v3 = count[i4 + 3];
        }
        int s0 = v0, s1 = s0 + v1, s2 = s1 + v2, s3 = s2 + v3;
        int sv = s3;
        #pragma unroll
        for (int off = 1; off < 64; off <<= 1) {
            int t = __shfl_up(sv, off, 64);
            if (lane >= off) sv += t;
        }
        if (lane == 63) wsum[wv] = sv;
        __syncthreads();
        if (tid < 16) {
            int ws = wsum[tid];
            #pragma unroll
            for (int off = 1; off < 16; off <<= 1) {
                int t = __shfl_up(ws, off, 64);
                if (tid >= off) ws += t;
            }
            wsum[tid] = ws;
        }
        __syncthreads();
        int add = carry + (wv ? wsum[wv - 1] : 0) + (sv - s3);
        if (i4     < n) { row_ptr[i4]     = add;      cursor[i4]     = add;      }
        if (i4 + 1 < n) { row_ptr[i4 + 1] = add + s0; cursor[i4 + 1] = add + s0; }
        if (i4 + 2 < n) { row_ptr[i4 + 2] = add + s1; cursor[i4 + 2] = add + s1; }
        if (i4 + 3 < n) { row_ptr[i4 + 3] = add + s2; cursor[i4 + 3] = add + s2; }
        carry += wsum[15];
        __syncthreads();
    }
    if (tid == 0) row_ptr[n] = carry;
}

// Scatter, XCD-sharded: replica r = blockIdx.x & 7 handles dst range
// [r*n/8,(r+1)*n/8) so each CSR region is written from one XCD (write-clean
// 64B lines). Emits int4 {src, ea_bits, dst, 0} per edge.
__global__ void scatter_kernel(const int* __restrict__ ei, const float* __restrict__ ea,
                               int* __restrict__ cursor, int4* __restrict__ cse,
                               int E, int n) {
    int r = blockIdx.x & 7;
    int nb = gridDim.x >> 3, cb = blockIdx.x >> 3;
    int rlo = r * n;                       // compare d*8 against [r*n, (r+1)*n)
    for (int j = cb * 256 + threadIdx.x; j < E; j += nb * 256) {
        int d = clampi(ei[E + j], 0, n - 1);
        int d8 = d << 3;
        if (d8 >= rlo && d8 < rlo + n) {
            int pos = atomicAdd(&cursor[d], 1);
            if (pos >= 0 && pos < E)
                cse[pos] = make_int4(clampi(ei[j], 0, n - 1), __float_as_int(ea[j]), d, 0);
        }
    }
}

// ---------------------------------------------------------------------------
// Pack both layers' weight matrices into per-lane MFMA B-fragments (bf16).
// elem i of lane l holds B[k][col], col = 16*(t&3)+(l&15),
// k = 32*h + 16*(i>>2) + 4*(l>>4) + (i&3).
// ---------------------------------------------------------------------------
__global__ void pack_weights(const float* __restrict__ Wq1, const float* __restrict__ Wk1,
                             const float* __restrict__ Wv1, const float* __restrict__ Ws1,
                             const float* __restrict__ Wq2, const float* __restrict__ Wk2,
                             const float* __restrict__ Wv2, const float* __restrict__ Ws2,
                             ushort* __restrict__ Bp1, ushort* __restrict__ Bp2) {
    int tid = blockIdx.x * blockDim.x + threadIdx.x;   // 0..4095
    if (tid >= 4096) return;
    int layer = tid >> 11;
    int t2 = tid & 2047;
    int lane = t2 & 63;
    int th = t2 >> 6;                  // t*2 + h
    int h = th & 1, t = th >> 1;
    const float* W = layer ? ((t < 4) ? Wq2 : (t < 8) ? Wk2 : (t < 12) ? Wv2 : Ws2)
                           : ((t < 4) ? Wq1 : (t < 8) ? Wk1 : (t < 12) ? Wv1 : Ws1);
    ushort* Bp = layer ? Bp2 : Bp1;
    int col = ((t & 3) << 4) + (lane & 15);
    int g = lane >> 4;
    #pragma unroll
    for (int i = 0; i < 8; ++i) {
        int k = 32 * h + 16 * (i >> 2) + 4 * g + (i & 3);
        Bp[t2 * 8 + i] = f2bf(W[k * 64 + col]);
    }
}

// ---------------------------------------------------------------------------
// Node transform via MFMA, biases folded into the epilogue.
// One wave computes a 16-row x 256-col tile (Q|K|V|S) with 32 MFMAs.
// Outputs: Q f32, KV interleaved bf16 [row][128] (K=0..63, V=64..127), S f32,
// qWe = (Q+bq).We.  INF32: read f32 input and convert in-register.
// ---------------------------------------------------------------------------
template<bool INF32>
__global__ __launch_bounds__(256) void node_transform_mfma(
    const void* __restrict__ xin, const ushort* __restrict__ Bpack,
    const float* __restrict__ We,
    const float* __restrict__ bq, const float* __restrict__ bk,
    const float* __restrict__ bv, const float* __restrict__ bs,
    float* __restrict__ Q, ushort* __restrict__ KVb,
    float* __restrict__ S, float* __restrict__ qWe, int n)
{
    __shared__ bshort8 Blds[2048];    // 32 KiB
    {
        const bshort8* gB = (const bshort8*)Bpack;
        for (int i = threadIdx.x; i < 2048; i += 256) Blds[i] = gB[i];
    }
    __syncthreads();

    int lane = threadIdx.x & 63;
    int wv = threadIdx.x >> 6;
    int tile = blockIdx.x * 4 + wv;
    int ntiles = (n + 15) >> 4;
    if (tile >= ntiles) return;
    int r0 = tile << 4;
    int c = lane & 15, g = lane >> 4;

    int arow = r0 + c; if (arow >= n) arow = n - 1;
    union { ushort4 u[2]; bshort8 v; } A0, A1;
    if constexpr (INF32) {
        const float* xr = (const float*)xin + (size_t)arow * 64 + 4 * g;
        float4 f0 = *(const float4*)(xr);
        float4 f1 = *(const float4*)(xr + 16);
        float4 f2 = *(const float4*)(xr + 32);
        float4 f3 = *(const float4*)(xr + 48);
        A0.u[0] = make_ushort4(f2bf(f0.x), f2bf(f0.y), f2bf(f0.z), f2bf(f0.w));
        A0.u[1] = make_ushort4(f2bf(f1.x), f2bf(f1.y), f2bf(f1.z), f2bf(f1.w));
        A1.u[0] = make_ushort4(f2bf(f2.x), f2bf(f2.y), f2bf(f2.z), f2bf(f2.w));
        A1.u[1] = make_ushort4(f2bf(f3.x), f2bf(f3.y), f2bf(f3.z), f2bf(f3.w));
    } else {
        const ushort* xr = (const ushort*)xin + (size_t)arow * 64 + 4 * g;
        A0.u[0] = *(const ushort4*)(xr);
        A0.u[1] = *(const ushort4*)(xr + 16);
        A1.u[0] = *(const ushort4*)(xr + 32);
        A1.u[1] = *(const ushort4*)(xr + 48);
    }

    f32x4 acc[16];
    #pragma unroll
    for (int t = 0; t < 16; ++t) acc[t] = (f32x4){0.f, 0.f, 0.f, 0.f};
    #pragma unroll
    for (int t = 0; t < 16; ++t) {
        acc[t] = __builtin_amdgcn_mfma_f32_16x16x32_bf16(A0.v, Blds[(2 * t) * 64 + lane], acc[t], 0, 0, 0);
        acc[t] = __builtin_amdgcn_mfma_f32_16x16x32_bf16(A1.v, Blds[(2 * t + 1) * 64 + lane], acc[t], 0, 0, 0);
    }

    float we_c[4], bq_c[4];
    #pragma unroll
    for (int t = 0; t < 4; ++t) { we_c[t] = We[16 * t + c]; bq_c[t] = bq[16 * t + c]; }
    #pragma unroll
    for (int j = 0; j < 4; ++j) {
        float part = 0.f;
        #pragma unroll
        for (int t = 0; t < 4; ++t) part += (acc[t][j] + bq_c[t]) * we_c[t];
        part += __shfl_xor(part, 1);
        part += __shfl_xor(part, 2);
        part += __shfl_xor(part, 4);
        part += __shfl_xor(part, 8);
        int orow = r0 + 4 * g + j;
        if (c == 0 && orow < n) qWe[orow] = part;
    }

    #pragma unroll
    for (int tt = 0; tt < 4; ++tt) {
        int col = 16 * tt + c;
        float vbk = bk[col], vbv = bv[col], vbs = bs[col];
        #pragma unroll
        for (int j = 0; j < 4; ++j) {
            int orow = r0 + 4 * g + j;
            if (orow >= n) continue;
            size_t o = (size_t)orow * 64 + col;
            Q[o] = acc[tt][j] + bq_c[tt];
            KVb[(size_t)orow * 128 + col]      = f2bf(acc[4 + tt][j] + vbk);
            KVb[(size_t)orow * 128 + 64 + col] = f2bf(acc[8 + tt][j] + vbv);
            S[o] = acc[12 + tt][j] + vbs;
        }
    }
}

// ---------------------------------------------------------------------------
// Pass A: edge-parallel score. 8 lanes per edge, 8 edges per wave per iter.
// p[e] = exp((Q[dst].K[src] + ea*qWe[dst]) / 8). Latency hidden by E-way
// parallelism; consecutive CSR edges share dst -> Q row hits L1/L2.
// ---------------------------------------------------------------------------
__global__ __launch_bounds__(256) void score_kernel(
    const float* __restrict__ Q, const ushort* __restrict__ KVb,
    const float* __restrict__ qWe, const int4* __restrict__ cse,
    float* __restrict__ pA, int n, int E)
{
    int lane = threadIdx.x & 63;
    int g = lane >> 3, q8 = lane & 7;
    int wid = (blockIdx.x * blockDim.x + threadIdx.x) >> 6;
    int nw  = (gridDim.x * blockDim.x) >> 6;
    for (int e0 = wid * 8; e0 < E; e0 += nw * 8) {
        int e = e0 + g;
        bool valid = (e < E);
        int idx = valid ? e : 0;
        int4 ed = cse[idx];
        int sp  = clampi(ed.x, 0, n - 1);
        float ea = __int_as_float(ed.y);
        int dst = clampi(ed.z, 0, n - 1);
        const float4* Qrow = (const float4*)(Q + (size_t)dst * 64);
        float4 qA = Qrow[2 * q8], qB = Qrow[2 * q8 + 1];
        ushort8v k8 = *(const ushort8v*)(KVb + (size_t)sp * 128 + 8 * q8);
        float part = qA.x * bf2f(k8[0]) + qA.y * bf2f(k8[1])
                   + qA.z * bf2f(k8[2]) + qA.w * bf2f(k8[3])
                   + qB.x * bf2f(k8[4]) + qB.y * bf2f(k8[5])
                   + qB.z * bf2f(k8[6]) + qB.w * bf2f(k8[7]);
        part += __shfl_xor(part, 1);
        part += __shfl_xor(part, 2);
        part += __shfl_xor(part, 4);
        float score = fmaf(ea, qWe[dst], part) * 0.125f;
        if (valid && q8 == 0) pA[e] = __expf(score);
    }
}

// ---------------------------------------------------------------------------
// Pass B: node-parallel aggregate. Inner loop: coalesced p/cse reads + V
// gather + FMAs only (no shfl/exp) -> iterations pipeline freely.
// out = (sum p*V)/sum p + (sum p*ea)/sum p * We + S   (+relu, bf16 for L1).
// ---------------------------------------------------------------------------
template<int L1>
__global__ __launch_bounds__(256) void agg2_kernel(
    const ushort* __restrict__ KVb, const float* __restrict__ S,
    const float* __restrict__ pA, const float* __restrict__ We,
    const int* __restrict__ row_ptr, const int4* __restrict__ cse,
    void* __restrict__ outp, int n, int E)
{
    int lane = threadIdx.x & 63;
    int g = lane >> 3, q8 = lane & 7;
    int wid = (blockIdx.x * blockDim.x + threadIdx.x) >> 6;
    int nw  = (gridDim.x * blockDim.x) >> 6;
    float4 weA = ((const float4*)We)[2 * q8];
    float4 weB = ((const float4*)We)[2 * q8 + 1];

    for (int i = wid; i < n; i += nw) {
        int beg = clampi(row_ptr[i], 0, E);
        int end = clampi(row_ptr[i + 1], beg, E);
        f32x4 aA = {0.f, 0.f, 0.f, 0.f}, aB = {0.f, 0.f, 0.f, 0.f};
        float ssum = 0.f, sea = 0.f;

        for (int e0 = beg; e0 < end; e0 += 8) {
            int e = e0 + g;
            bool valid = (e < end);
            int idx = valid ? e : beg;
            float p = pA[idx];
            if (!valid) p = 0.f;
            int4 ed = cse[idx];
            int sp = clampi(ed.x, 0, n - 1);
            float ea = __int_as_float(ed.y);
            ushort8v v8 = *(const ushort8v*)(KVb + (size_t)sp * 128 + 64 + 8 * q8);
            ssum += p;
            sea = fmaf(p, ea, sea);
            aA[0] = fmaf(p, bf2f(v8[0]), aA[0]);
            aA[1] = fmaf(p, bf2f(v8[1]), aA[1]);
            aA[2] = fmaf(p, bf2f(v8[2]), aA[2]);
            aA[3] = fmaf(p, bf2f(v8[3]), aA[3]);
            aB[0] = fmaf(p, bf2f(v8[4]), aB[0]);
            aB[1] = fmaf(p, bf2f(v8[5]), aB[1]);
            aB[2] = fmaf(p, bf2f(v8[6]), aB[2]);
            aB[3] = fmaf(p, bf2f(v8[7]), aB[3]);
        }

        ssum = xgrp(ssum); sea = xgrp(sea);
        #pragma unroll
        for (int t = 0; t < 4; ++t) { aA[t] = xgrp(aA[t]); aB[t] = xgrp(aB[t]); }
        float inv = (ssum > 0.f) ? 1.f / ssum : 0.f;
        float eawe = sea * inv;
        const float4* Srow = (const float4*)(S + (size_t)i * 64);
        float4 sA = Srow[2 * q8], sB = Srow[2 * q8 + 1];
        float o0 = fmaf(aA[0], inv, fmaf(eawe, weA.x, sA.x));
        float o1 = fmaf(aA[1], inv, fmaf(eawe, weA.y, sA.y));
        float o2 = fmaf(aA[2], inv, fmaf(eawe, weA.z, sA.z));
        float o3 = fmaf(aA[3], inv, fmaf(eawe, weA.w, sA.w));
        float o4 = fmaf(aB[0], inv, fmaf(eawe, weB.x, sB.x));
        float o5 = fmaf(aB[1], inv, fmaf(eawe, weB.y, sB.y));
        float o6 = fmaf(aB[2], inv, fmaf(eawe, weB.z, sB.z));
        float o7 = fmaf(aB[3], inv, fmaf(eawe, weB.w, sB.w));
        if (L1) {
            o0 = fmaxf(o0, 0.f); o1 = fmaxf(o1, 0.f); o2 = fmaxf(o2, 0.f); o3 = fmaxf(o3, 0.f);
            o4 = fmaxf(o4, 0.f); o5 = fmaxf(o5, 0.f); o6 = fmaxf(o6, 0.f); o7 = fmaxf(o7, 0.f);
            if (g == 0) {
                union { ushort u[8]; ushort8v v; } ov;
                ov.u[0] = f2bf(o0); ov.u[1] = f2bf(o1); ov.u[2] = f2bf(o2); ov.u[3] = f2bf(o3);
                ov.u[4] = f2bf(o4); ov.u[5] = f2bf(o5); ov.u[6] = f2bf(o6); ov.u[7] = f2bf(o7);
                *(ushort8v*)((ushort*)outp + (size_t)i * 64 + 8 * q8) = ov.v;
            }
        } else {
            if (g == 0) {
                float4* Or = (float4*)((float*)outp + (size_t)i * 64);
                Or[2 * q8]     = make_float4(o0, o1, o2, o3);
                Or[2 * q8 + 1] = make_float4(o4, o5, o6, o7);
            }
        }
    }
}

// ---------------------------------------------------------------------------
extern "C" void kernel_launch(void* const* d_in, const int* in_sizes, int n_in,
                              void* d_out, int out_size, void* d_ws, size_t ws_size,
                              hipStream_t stream) {
    const float* x   = (const float*)d_in[0];
    const int*   ei  = (const int*)d_in[1];     // int32 on device
    const float* ea  = (const float*)d_in[2];
    const float *Wq1 = (const float*)d_in[3],  *bq1 = (const float*)d_in[4];
    const float *Wk1 = (const float*)d_in[5],  *bk1 = (const float*)d_in[6];
    const float *Wv1 = (const float*)d_in[7],  *bv1 = (const float*)d_in[8];
    const float *We1 = (const float*)d_in[9];
    const float *Ws1 = (const float*)d_in[10], *bs1 = (const float*)d_in[11];
    const float *Wq2 = (const float*)d_in[12], *bq2 = (const float*)d_in[13];
    const float *Wk2 = (const float*)d_in[14], *bk2 = (const float*)d_in[15];
    const float *Wv2 = (const float*)d_in[16], *bv2 = (const float*)d_in[17];
    const float *We2 = (const float*)d_in[18];
    const float *Ws2 = (const float*)d_in[19], *bs2 = (const float*)d_in[20];

    const int N_ = in_sizes[0] / 64;   // 50000
    const int E_ = in_sizes[2];        // 800000

    char* wsb = (char*)d_ws;
    size_t off = 0;
    auto carve = [&](size_t bytes) -> void* {
        void* p = (void*)(wsb + off);
        off += (bytes + 255) & ~(size_t)255;
        return p;
    };
    float*  Q    = (float*)carve((size_t)N_ * 64 * 4);
    float*  S    = (float*)carve((size_t)N_ * 64 * 4);
    ushort* KVb  = (ushort*)carve((size_t)N_ * 128 * 2);
    ushort* hb   = (ushort*)carve((size_t)N_ * 64 * 2);
    float*  qWe  = (float*)carve((size_t)N_ * 4);
    float*  pA   = (float*)carve((size_t)E_ * 4);
    int*    count   = (int*)carve((size_t)N_ * 4);
    int*    row_ptr = (int*)carve((size_t)(N_ + 1) * 4);
    int*    cursor  = (int*)carve((size_t)N_ * 4);
    int4*   cse     = (int4*)carve((size_t)E_ * 16);
    ushort* Bp1     = (ushort*)carve(2048 * 8 * 2);
    ushort* Bp2     = (ushort*)carve(2048 * 8 * 2);
    (void)ws_size; (void)n_in; (void)out_size;

    hipMemsetAsync(count, 0, (size_t)N_ * 4, stream);
    pack_weights<<<16, 256, 0, stream>>>(Wq1, Wk1, Wv1, Ws1, Wq2, Wk2, Wv2, Ws2, Bp1, Bp2);

    // CSR build
    hist_kernel<<<(E_ + 255) / 256, 256, 0, stream>>>(ei, count, E_, N_);
    scan_exclusive<<<1, 1024, 0, stream>>>(count, row_ptr, cursor, N_);
    scatter_kernel<<<3136, 256, 0, stream>>>(ei, ea, cursor, cse, E_, N_);

    int ntb = (((N_ + 15) / 16) + 3) / 4;

    // Layer 1
    node_transform_mfma<true><<<ntb, 256, 0, stream>>>(x, Bp1, We1, bq1, bk1, bv1, bs1,
                                                       Q, KVb, S, qWe, N_);
    score_kernel<<<2048, 256, 0, stream>>>(Q, KVb, qWe, cse, pA, N_, E_);
    agg2_kernel<1><<<2048, 256, 0, stream>>>(KVb, S, pA, We1, row_ptr, cse, hb, N_, E_);
    // Layer 2
    node_transform_mfma<false><<<ntb, 256, 0, stream>>>(hb, Bp2, We2, bq2, bk2, bv2, bs2,
                                                        Q, KVb, S, qWe, N_);
    score_kernel<<<2048, 256, 0, stream>>>(Q, KVb, qWe, cse, pA, N_, E_);
    agg2_kernel<0><<<2048, 256, 0, stream>>>(KVb, S, pA, We2, row_ptr, cse, d_out, N_, E_);
}

// Round 9
// 259.683 us; speedup vs baseline: 4.3934x; 1.0023x over previous
//
#include <hip/hip_runtime.h>
#include <hip/hip_bf16.h>

typedef short bshort8 __attribute__((ext_vector_type(8)));
typedef float f32x4 __attribute__((ext_vector_type(4)));
typedef unsigned short ushort8v __attribute__((ext_vector_type(8)));

__device__ __forceinline__ int clampi(int v, int lo, int hi) {
    return v < lo ? lo : (v > hi ? hi : v);
}
__device__ __forceinline__ ushort f2bf(float f) {           // RNE f32 -> bf16 bits
    uint u = __float_as_uint(f);
    return (ushort)((u + 0x7FFFu + ((u >> 16) & 1u)) >> 16);
}
__device__ __forceinline__ float bf2f(ushort b) { return __uint_as_float(((uint)b) << 16); }

// ---------------------------------------------------------------------------
// Tiny zero-fill (hipMemsetAsync's blit kernel costs ~42us for 200KB!)
// ---------------------------------------------------------------------------
__global__ void zero_kernel(int* __restrict__ p, int n) {
    int i = blockIdx.x * blockDim.x + threadIdx.x;
    if (i < n) p[i] = 0;
}

// ---------------------------------------------------------------------------
// CSR build. hist: plain device-scope atomics (one coalesced pass).
// ---------------------------------------------------------------------------
__global__ void hist_kernel(const int* __restrict__ ei, int* __restrict__ count,
                            int E, int n) {
    int j = blockIdx.x * blockDim.x + threadIdx.x;
    if (j < E) {
        int d = clampi(ei[E + j], 0, n - 1);
        atomicAdd(&count[d], 1);
    }
}

// Exclusive scan, single block of 1024 threads, 4 elements per thread per pass.
__global__ void scan_exclusive(const int* __restrict__ count, int* __restrict__ row_ptr,
                               int* __restrict__ cursor, int n) {
    __shared__ int wsum[16];
    int tid = threadIdx.x, lane = tid & 63, wv = tid >> 6;
    int carry = 0;
    for (int base = 0; base < n; base += 4096) {
        int i4 = base + tid * 4;
        int v0 = 0, v1 = 0, v2 = 0, v3 = 0;
        if (i4 + 3 < n) {
            int4 t = *(const int4*)(count + i4);
            v0 = t.x; v1 = t.y; v2 = t.z; v3 = t.w;
        } else {
            if (i4     < n) v0 = count[i4];
            if (i4 + 1 < n) v1 = count[i4 + 1];
            if (i4 + 2 < n) v2 = count[i4 + 2];
            if (i4 + 3 < n) v3 = count[i4 + 3];
        }
        int s0 = v0, s1 = s0 + v1, s2 = s1 + v2, s3 = s2 + v3;
        int sv = s3;
        #pragma unroll
        for (int off = 1; off < 64; off <<= 1) {
            int t = __shfl_up(sv, off, 64);
            if (lane >= off) sv += t;
        }
        if (lane == 63) wsum[wv] = sv;
        __syncthreads();
        if (tid < 16) {
            int ws = wsum[tid];
            #pragma unroll
            for (int off = 1; off < 16; off <<= 1) {
                int t = __shfl_up(ws, off, 64);
                if (tid >= off) ws += t;
            }
            wsum[tid] = ws;
        }
        __syncthreads();
        int add = carry + (wv ? wsum[wv - 1] : 0) + (sv - s3);
        if (i4     < n) { row_ptr[i4]     = add;      cursor[i4]     = add;      }
        if (i4 + 1 < n) { row_ptr[i4 + 1] = add + s0; cursor[i4 + 1] = add + s0; }
        if (i4 + 2 < n) { row_ptr[i4 + 2] = add + s1; cursor[i4 + 2] = add + s1; }
        if (i4 + 3 < n) { row_ptr[i4 + 3] = add + s2; cursor[i4 + 3] = add + s2; }
        carry += wsum[15];
        __syncthreads();
    }
    if (tid == 0) row_ptr[n] = carry;
}

// Scatter, XCD-sharded: replica r = blockIdx.x & 7 handles dst range
// [r*n/8,(r+1)*n/8) so each CSR region is written from one XCD (write-clean
// 64B lines). Emits int4 {src, ea_bits, dst, 0} per edge.
__global__ void scatter_kernel(const int* __restrict__ ei, const float* __restrict__ ea,
                               int* __restrict__ cursor, int4* __restrict__ cse,
                               int E, int n) {
    int r = blockIdx.x & 7;
    int nb = gridDim.x >> 3, cb = blockIdx.x >> 3;
    int rlo = r * n;                       // compare d*8 against [r*n, (r+1)*n)
    for (int j = cb * 256 + threadIdx.x; j < E; j += nb * 256) {
        int d = clampi(ei[E + j], 0, n - 1);
        int d8 = d << 3;
        if (d8 >= rlo && d8 < rlo + n) {
            int pos = atomicAdd(&cursor[d], 1);
            if (pos >= 0 && pos < E)
                cse[pos] = make_int4(clampi(ei[j], 0, n - 1), __float_as_int(ea[j]), d, 0);
        }
    }
}

// ---------------------------------------------------------------------------
// Pack both layers' weight matrices into per-lane MFMA B-fragments (bf16).
// elem i of lane l holds B[k][col], col = 16*(t&3)+(l&15),
// k = 32*h + 16*(i>>2) + 4*(l>>4) + (i&3).
// ---------------------------------------------------------------------------
__global__ void pack_weights(const float* __restrict__ Wq1, const float* __restrict__ Wk1,
                             const float* __restrict__ Wv1, const float* __restrict__ Ws1,
                             const float* __restrict__ Wq2, const float* __restrict__ Wk2,
                             const float* __restrict__ Wv2, const float* __restrict__ Ws2,
                             ushort* __restrict__ Bp1, ushort* __restrict__ Bp2) {
    int tid = blockIdx.x * blockDim.x + threadIdx.x;   // 0..4095
    if (tid >= 4096) return;
    int layer = tid >> 11;
    int t2 = tid & 2047;
    int lane = t2 & 63;
    int th = t2 >> 6;                  // t*2 + h
    int h = th & 1, t = th >> 1;
    const float* W = layer ? ((t < 4) ? Wq2 : (t < 8) ? Wk2 : (t < 12) ? Wv2 : Ws2)
                           : ((t < 4) ? Wq1 : (t < 8) ? Wk1 : (t < 12) ? Wv1 : Ws1);
    ushort* Bp = layer ? Bp2 : Bp1;
    int col = ((t & 3) << 4) + (lane & 15);
    int g = lane >> 4;
    #pragma unroll
    for (int i = 0; i < 8; ++i) {
        int k = 32 * h + 16 * (i >> 2) + 4 * g + (i & 3);
        Bp[t2 * 8 + i] = f2bf(W[k * 64 + col]);
    }
}

// ---------------------------------------------------------------------------
// Node transform via MFMA, biases folded into the epilogue.
// One wave computes a 16-row x 256-col tile (Q|K|V|S) with 32 MFMAs.
// Outputs: Q f32, KV interleaved bf16 [row][128] (K=0..63, V=64..127), S f32,
// qWe = (Q+bq).We.  INF32: read f32 input and convert in-register.
// ---------------------------------------------------------------------------
template<bool INF32>
__global__ __launch_bounds__(256) void node_transform_mfma(
    const void* __restrict__ xin, const ushort* __restrict__ Bpack,
    const float* __restrict__ We,
    const float* __restrict__ bq, const float* __restrict__ bk,
    const float* __restrict__ bv, const float* __restrict__ bs,
    float* __restrict__ Q, ushort* __restrict__ KVb,
    float* __restrict__ S, float* __restrict__ qWe, int n)
{
    __shared__ bshort8 Blds[2048];    // 32 KiB
    {
        const bshort8* gB = (const bshort8*)Bpack;
        for (int i = threadIdx.x; i < 2048; i += 256) Blds[i] = gB[i];
    }
    __syncthreads();

    int lane = threadIdx.x & 63;
    int wv = threadIdx.x >> 6;
    int tile = blockIdx.x * 4 + wv;
    int ntiles = (n + 15) >> 4;
    if (tile >= ntiles) return;
    int r0 = tile << 4;
    int c = lane & 15, g = lane >> 4;

    int arow = r0 + c; if (arow >= n) arow = n - 1;
    union { ushort4 u[2]; bshort8 v; } A0, A1;
    if constexpr (INF32) {
        const float* xr = (const float*)xin + (size_t)arow * 64 + 4 * g;
        float4 f0 = *(const float4*)(xr);
        float4 f1 = *(const float4*)(xr + 16);
        float4 f2 = *(const float4*)(xr + 32);
        float4 f3 = *(const float4*)(xr + 48);
        A0.u[0] = make_ushort4(f2bf(f0.x), f2bf(f0.y), f2bf(f0.z), f2bf(f0.w));
        A0.u[1] = make_ushort4(f2bf(f1.x), f2bf(f1.y), f2bf(f1.z), f2bf(f1.w));
        A1.u[0] = make_ushort4(f2bf(f2.x), f2bf(f2.y), f2bf(f2.z), f2bf(f2.w));
        A1.u[1] = make_ushort4(f2bf(f3.x), f2bf(f3.y), f2bf(f3.z), f2bf(f3.w));
    } else {
        const ushort* xr = (const ushort*)xin + (size_t)arow * 64 + 4 * g;
        A0.u[0] = *(const ushort4*)(xr);
        A0.u[1] = *(const ushort4*)(xr + 16);
        A1.u[0] = *(const ushort4*)(xr + 32);
        A1.u[1] = *(const ushort4*)(xr + 48);
    }

    f32x4 acc[16];
    #pragma unroll
    for (int t = 0; t < 16; ++t) acc[t] = (f32x4){0.f, 0.f, 0.f, 0.f};
    #pragma unroll
    for (int t = 0; t < 16; ++t) {
        acc[t] = __builtin_amdgcn_mfma_f32_16x16x32_bf16(A0.v, Blds[(2 * t) * 64 + lane], acc[t], 0, 0, 0);
        acc[t] = __builtin_amdgcn_mfma_f32_16x16x32_bf16(A1.v, Blds[(2 * t + 1) * 64 + lane], acc[t], 0, 0, 0);
    }

    float we_c[4], bq_c[4];
    #pragma unroll
    for (int t = 0; t < 4; ++t) { we_c[t] = We[16 * t + c]; bq_c[t] = bq[16 * t + c]; }
    #pragma unroll
    for (int j = 0; j < 4; ++j) {
        float part = 0.f;
        #pragma unroll
        for (int t = 0; t < 4; ++t) part += (acc[t][j] + bq_c[t]) * we_c[t];
        part += __shfl_xor(part, 1);
        part += __shfl_xor(part, 2);
        part += __shfl_xor(part, 4);
        part += __shfl_xor(part, 8);
        int orow = r0 + 4 * g + j;
        if (c == 0 && orow < n) qWe[orow] = part;
    }

    #pragma unroll
    for (int tt = 0; tt < 4; ++tt) {
        int col = 16 * tt + c;
        float vbk = bk[col], vbv = bv[col], vbs = bs[col];
        #pragma unroll
        for (int j = 0; j < 4; ++j) {
            int orow = r0 + 4 * g + j;
            if (orow >= n) continue;
            size_t o = (size_t)orow * 64 + col;
            Q[o] = acc[tt][j] + bq_c[tt];
            KVb[(size_t)orow * 128 + col]      = f2bf(acc[4 + tt][j] + vbk);
            KVb[(size_t)orow * 128 + 64 + col] = f2bf(acc[8 + tt][j] + vbv);
            S[o] = acc[12 + tt][j] + vbs;
        }
    }
}

// ---------------------------------------------------------------------------
// Pass A: edge-parallel score. 8 lanes per edge, 8 edges per wave per iter.
// p[e] = exp((Q[dst].K[src] + ea*qWe[dst]) / 8). Latency hidden by E-way
// parallelism; consecutive CSR edges share dst -> Q row hits L1/L2.
// ---------------------------------------------------------------------------
__global__ __launch_bounds__(256) void score_kernel(
    const float* __restrict__ Q, const ushort* __restrict__ KVb,
    const float* __restrict__ qWe, const int4* __restrict__ cse,
    float* __restrict__ pA, int n, int E)
{
    int lane = threadIdx.x & 63;
    int g = lane >> 3, q8 = lane & 7;
    int wid = (blockIdx.x * blockDim.x + threadIdx.x) >> 6;
    int nw  = (gridDim.x * blockDim.x) >> 6;
    for (int e0 = wid * 8; e0 < E; e0 += nw * 8) {
        int e = e0 + g;
        bool valid = (e < E);
        int idx = valid ? e : 0;
        int4 ed = cse[idx];
        int sp  = clampi(ed.x, 0, n - 1);
        float ea = __int_as_float(ed.y);
        int dst = clampi(ed.z, 0, n - 1);
        const float4* Qrow = (const float4*)(Q + (size_t)dst * 64);
        float4 qA = Qrow[2 * q8], qB = Qrow[2 * q8 + 1];
        ushort8v k8 = *(const ushort8v*)(KVb + (size_t)sp * 128 + 8 * q8);
        float part = qA.x * bf2f(k8[0]) + qA.y * bf2f(k8[1])
                   + qA.z * bf2f(k8[2]) + qA.w * bf2f(k8[3])
                   + qB.x * bf2f(k8[4]) + qB.y * bf2f(k8[5])
                   + qB.z * bf2f(k8[6]) + qB.w * bf2f(k8[7]);
        part += __shfl_xor(part, 1);
        part += __shfl_xor(part, 2);
        part += __shfl_xor(part, 4);
        float score = fmaf(ea, qWe[dst], part) * 0.125f;
        if (valid && q8 == 0) pA[e] = __expf(score);
    }
}

// ---------------------------------------------------------------------------
// Pass B: node-parallel aggregate, one 8-lane group per node. p/ea/cse are
// group-broadcast loads; each lane owns 8 output columns -> NO cross-lane
// shuffles at all (ssum/sea are computed redundantly in every lane).
// out = (sum p*V)/sum p + (sum p*ea)/sum p * We + S   (+relu, bf16 for L1).
// ---------------------------------------------------------------------------
template<int L1>
__global__ __launch_bounds__(256) void agg2_kernel(
    const ushort* __restrict__ KVb, const float* __restrict__ S,
    const float* __restrict__ pA, const float* __restrict__ We,
    const int* __restrict__ row_ptr, const int4* __restrict__ cse,
    void* __restrict__ outp, int n, int E)
{
    int q8 = threadIdx.x & 7;
    int gid = (blockIdx.x * blockDim.x + threadIdx.x) >> 3;
    int ng  = (gridDim.x * blockDim.x) >> 3;
    float4 weA = ((const float4*)We)[2 * q8];
    float4 weB = ((const float4*)We)[2 * q8 + 1];

    for (int i = gid; i < n; i += ng) {
        int beg = clampi(row_ptr[i], 0, E);
        int end = clampi(row_ptr[i + 1], beg, E);
        f32x4 aA = {0.f, 0.f, 0.f, 0.f}, aB = {0.f, 0.f, 0.f, 0.f};
        float ssum = 0.f, sea = 0.f;

        for (int e = beg; e < end; ++e) {
            float p = pA[e];
            int4 ed = cse[e];
            int sp = clampi(ed.x, 0, n - 1);
            float ea = __int_as_float(ed.y);
            ushort8v v8 = *(const ushort8v*)(KVb + (size_t)sp * 128 + 64 + 8 * q8);
            ssum += p;
            sea = fmaf(p, ea, sea);
            aA[0] = fmaf(p, bf2f(v8[0]), aA[0]);
            aA[1] = fmaf(p, bf2f(v8[1]), aA[1]);
            aA[2] = fmaf(p, bf2f(v8[2]), aA[2]);
            aA[3] = fmaf(p, bf2f(v8[3]), aA[3]);
            aB[0] = fmaf(p, bf2f(v8[4]), aB[0]);
            aB[1] = fmaf(p, bf2f(v8[5]), aB[1]);
            aB[2] = fmaf(p, bf2f(v8[6]), aB[2]);
            aB[3] = fmaf(p, bf2f(v8[7]), aB[3]);
        }

        float inv = (ssum > 0.f) ? 1.f / ssum : 0.f;
        float eawe = sea * inv;
        const float4* Srow = (const float4*)(S + (size_t)i * 64);
        float4 sA = Srow[2 * q8], sB = Srow[2 * q8 + 1];
        float o0 = fmaf(aA[0], inv, fmaf(eawe, weA.x, sA.x));
        float o1 = fmaf(aA[1], inv, fmaf(eawe, weA.y, sA.y));
        float o2 = fmaf(aA[2], inv, fmaf(eawe, weA.z, sA.z));
        float o3 = fmaf(aA[3], inv, fmaf(eawe, weA.w, sA.w));
        float o4 = fmaf(aB[0], inv, fmaf(eawe, weB.x, sB.x));
        float o5 = fmaf(aB[1], inv, fmaf(eawe, weB.y, sB.y));
        float o6 = fmaf(aB[2], inv, fmaf(eawe, weB.z, sB.z));
        float o7 = fmaf(aB[3], inv, fmaf(eawe, weB.w, sB.w));
        if (L1) {
            o0 = fmaxf(o0, 0.f); o1 = fmaxf(o1, 0.f); o2 = fmaxf(o2, 0.f); o3 = fmaxf(o3, 0.f);
            o4 = fmaxf(o4, 0.f); o5 = fmaxf(o5, 0.f); o6 = fmaxf(o6, 0.f); o7 = fmaxf(o7, 0.f);
            union { ushort u[8]; ushort8v v; } ov;
            ov.u[0] = f2bf(o0); ov.u[1] = f2bf(o1); ov.u[2] = f2bf(o2); ov.u[3] = f2bf(o3);
            ov.u[4] = f2bf(o4); ov.u[5] = f2bf(o5); ov.u[6] = f2bf(o6); ov.u[7] = f2bf(o7);
            *(ushort8v*)((ushort*)outp + (size_t)i * 64 + 8 * q8) = ov.v;
        } else {
            float4* Or = (float4*)((float*)outp + (size_t)i * 64);
            Or[2 * q8]     = make_float4(o0, o1, o2, o3);
            Or[2 * q8 + 1] = make_float4(o4, o5, o6, o7);
        }
    }
}

// ---------------------------------------------------------------------------
extern "C" void kernel_launch(void* const* d_in, const int* in_sizes, int n_in,
                              void* d_out, int out_size, void* d_ws, size_t ws_size,
                              hipStream_t stream) {
    const float* x   = (const float*)d_in[0];
    const int*   ei  = (const int*)d_in[1];     // int32 on device
    const float* ea  = (const float*)d_in[2];
    const float *Wq1 = (const float*)d_in[3],  *bq1 = (const float*)d_in[4];
    const float *Wk1 = (const float*)d_in[5],  *bk1 = (const float*)d_in[6];
    const float *Wv1 = (const float*)d_in[7],  *bv1 = (const float*)d_in[8];
    const float *We1 = (const float*)d_in[9];
    const float *Ws1 = (const float*)d_in[10], *bs1 = (const float*)d_in[11];
    const float *Wq2 = (const float*)d_in[12], *bq2 = (const float*)d_in[13];
    const float *Wk2 = (const float*)d_in[14], *bk2 = (const float*)d_in[15];
    const float *Wv2 = (const float*)d_in[16], *bv2 = (const float*)d_in[17];
    const float *We2 = (const float*)d_in[18];
    const float *Ws2 = (const float*)d_in[19], *bs2 = (const float*)d_in[20];

    const int N_ = in_sizes[0] / 64;   // 50000
    const int E_ = in_sizes[2];        // 800000

    char* wsb = (char*)d_ws;
    size_t off = 0;
    auto carve = [&](size_t bytes) -> void* {
        void* p = (void*)(wsb + off);
        off += (bytes + 255) & ~(size_t)255;
        return p;
    };
    float*  Q    = (float*)carve((size_t)N_ * 64 * 4);
    float*  S    = (float*)carve((size_t)N_ * 64 * 4);
    ushort* KVb  = (ushort*)carve((size_t)N_ * 128 * 2);
    ushort* hb   = (ushort*)carve((size_t)N_ * 64 * 2);
    float*  qWe  = (float*)carve((size_t)N_ * 4);
    float*  pA   = (float*)carve((size_t)E_ * 4);
    int*    count   = (int*)carve((size_t)N_ * 4);
    int*    row_ptr = (int*)carve((size_t)(N_ + 1) * 4);
    int*    cursor  = (int*)carve((size_t)N_ * 4);
    int4*   cse     = (int4*)carve((size_t)E_ * 16);
    ushort* Bp1     = (ushort*)carve(2048 * 8 * 2);
    ushort* Bp2     = (ushort*)carve(2048 * 8 * 2);
    (void)ws_size; (void)n_in; (void)out_size;

    zero_kernel<<<(N_ + 255) / 256, 256, 0, stream>>>(count, N_);
    pack_weights<<<16, 256, 0, stream>>>(Wq1, Wk1, Wv1, Ws1, Wq2, Wk2, Wv2, Ws2, Bp1, Bp2);

    // CSR build
    hist_kernel<<<(E_ + 255) / 256, 256, 0, stream>>>(ei, count, E_, N_);
    scan_exclusive<<<1, 1024, 0, stream>>>(count, row_ptr, cursor, N_);
    scatter_kernel<<<3136, 256, 0, stream>>>(ei, ea, cursor, cse, E_, N_);

    int ntb = (((N_ + 15) / 16) + 3) / 4;

    // Layer 1
    node_transform_mfma<true><<<ntb, 256, 0, stream>>>(x, Bp1, We1, bq1, bk1, bv1, bs1,
                                                       Q, KVb, S, qWe, N_);
    score_kernel<<<2048, 256, 0, stream>>>(Q, KVb, qWe, cse, pA, N_, E_);
    agg2_kernel<1><<<1568, 256, 0, stream>>>(KVb, S, pA, We1, row_ptr, cse, hb, N_, E_);
    // Layer 2
    node_transform_mfma<false><<<ntb, 256, 0, stream>>>(hb, Bp2, We2, bq2, bk2, bv2, bs2,
                                                        Q, KVb, S, qWe, N_);
    score_kernel<<<2048, 256, 0, stream>>>(Q, KVb, qWe, cse, pA, N_, E_);
    agg2_kernel<0><<<1568, 256, 0, stream>>>(KVb, S, pA, We2, row_ptr, cse, d_out, N_, E_);
}

// Round 10
// 232.928 us; speedup vs baseline: 4.8981x; 1.1149x over previous
//
#include <hip/hip_runtime.h>
#include <hip/hip_bf16.h>

typedef short bshort8 __attribute__((ext_vector_type(8)));
typedef float f32x4 __attribute__((ext_vector_type(4)));
typedef unsigned short ushort8v __attribute__((ext_vector_type(8)));

__device__ __forceinline__ int clampi(int v, int lo, int hi) {
    return v < lo ? lo : (v > hi ? hi : v);
}
__device__ __forceinline__ ushort f2bf(float f) {           // RNE f32 -> bf16 bits
    uint u = __float_as_uint(f);
    return (ushort)((u + 0x7FFFu + ((u >> 16) & 1u)) >> 16);
}
__device__ __forceinline__ float bf2f(ushort b) { return __uint_as_float(((uint)b) << 16); }

// ---------------------------------------------------------------------------
// Pack both layers' weights into per-lane MFMA B-fragments (blocks 0..15) and
// zero the histogram counters (blocks >= 16). One launch instead of two.
// Fragment layout (mfma_f32_16x16x32_bf16): elem i of lane l holds B[k][col],
// col = 16*(t&3)+(l&15), k = 32*h + 16*(i>>2) + 4*(l>>4) + (i&3).
// ---------------------------------------------------------------------------
__global__ void pack_and_zero(const float* __restrict__ Wq1, const float* __restrict__ Wk1,
                              const float* __restrict__ Wv1, const float* __restrict__ Ws1,
                              const float* __restrict__ Wq2, const float* __restrict__ Wk2,
                              const float* __restrict__ Wv2, const float* __restrict__ Ws2,
                              ushort* __restrict__ Bp1, ushort* __restrict__ Bp2,
                              int* __restrict__ count, int n) {
    if (blockIdx.x >= 16) {
        int j = (blockIdx.x - 16) * 256 + threadIdx.x;
        if (j < n) count[j] = 0;
        return;
    }
    int tid = blockIdx.x * 256 + threadIdx.x;          // 0..4095
    int layer = tid >> 11;
    int t2 = tid & 2047;
    int lane = t2 & 63;
    int th = t2 >> 6;                  // t*2 + h
    int h = th & 1, t = th >> 1;
    const float* W = layer ? ((t < 4) ? Wq2 : (t < 8) ? Wk2 : (t < 12) ? Wv2 : Ws2)
                           : ((t < 4) ? Wq1 : (t < 8) ? Wk1 : (t < 12) ? Wv1 : Ws1);
    ushort* Bp = layer ? Bp2 : Bp1;
    int col = ((t & 3) << 4) + (lane & 15);
    int g = lane >> 4;
    #pragma unroll
    for (int i = 0; i < 8; ++i) {
        int k = 32 * h + 16 * (i >> 2) + 4 * g + (i & 3);
        Bp[t2 * 8 + i] = f2bf(W[k * 64 + col]);
    }
}

// ---------------------------------------------------------------------------
// CSR build. hist: plain device-scope atomics (one coalesced pass).
// ---------------------------------------------------------------------------
__global__ void hist_kernel(const int* __restrict__ ei, int* __restrict__ count,
                            int E, int n) {
    int j = blockIdx.x * blockDim.x + threadIdx.x;
    if (j < E) {
        int d = clampi(ei[E + j], 0, n - 1);
        atomicAdd(&count[d], 1);
    }
}

// Exclusive scan, single block of 1024 threads, 4 elements per thread per pass.
__global__ void scan_exclusive(const int* __restrict__ count, int* __restrict__ row_ptr,
                               int* __restrict__ cursor, int n) {
    __shared__ int wsum[16];
    int tid = threadIdx.x, lane = tid & 63, wv = tid >> 6;
    int carry = 0;
    for (int base = 0; base < n; base += 4096) {
        int i4 = base + tid * 4;
        int v0 = 0, v1 = 0, v2 = 0, v3 = 0;
        if (i4 + 3 < n) {
            int4 t = *(const int4*)(count + i4);
            v0 = t.x; v1 = t.y; v2 = t.z; v3 = t.w;
        } else {
            if (i4     < n) v0 = count[i4];
            if (i4 + 1 < n) v1 = count[i4 + 1];
            if (i4 + 2 < n) v2 = count[i4 + 2];
            if (i4 + 3 < n) v3 = count[i4 + 3];
        }
        int s0 = v0, s1 = s0 + v1, s2 = s1 + v2, s3 = s2 + v3;
        int sv = s3;
        #pragma unroll
        for (int off = 1; off < 64; off <<= 1) {
            int t = __shfl_up(sv, off, 64);
            if (lane >= off) sv += t;
        }
        if (lane == 63) wsum[wv] = sv;
        __syncthreads();
        if (tid < 16) {
            int ws = wsum[tid];
            #pragma unroll
            for (int off = 1; off < 16; off <<= 1) {
                int t = __shfl_up(ws, off, 64);
                if (tid >= off) ws += t;
            }
            wsum[tid] = ws;
        }
        __syncthreads();
        int add = carry + (wv ? wsum[wv - 1] : 0) + (sv - s3);
        if (i4     < n) { row_ptr[i4]     = add;      cursor[i4]     = add;      }
        if (i4 + 1 < n) { row_ptr[i4 + 1] = add + s0; cursor[i4 + 1] = add + s0; }
        if (i4 + 2 < n) { row_ptr[i4 + 2] = add + s1; cursor[i4 + 2] = add + s1; }
        if (i4 + 3 < n) { row_ptr[i4 + 3] = add + s2; cursor[i4 + 3] = add + s2; }
        carry += wsum[15];
        __syncthreads();
    }
    if (tid == 0) row_ptr[n] = carry;
}

// Scatter, XCD-sharded: replica r = blockIdx.x & 7 handles dst range
// [r*n/8,(r+1)*n/8) so each CSR region is written from one XCD (write-clean
// 64B lines). Emits int2 {src, ea_bits} per edge (dst is implicit in CSR).
__global__ void scatter_kernel(const int* __restrict__ ei, const float* __restrict__ ea,
                               int* __restrict__ cursor, int2* __restrict__ cse,
                               int E, int n) {
    int r = blockIdx.x & 7;
    int nb = gridDim.x >> 3, cb = blockIdx.x >> 3;
    int rlo = r * n;                       // compare d*8 against [r*n, (r+1)*n)
    for (int j = cb * 256 + threadIdx.x; j < E; j += nb * 256) {
        int d = clampi(ei[E + j], 0, n - 1);
        int d8 = d << 3;
        if (d8 >= rlo && d8 < rlo + n) {
            int pos = atomicAdd(&cursor[d], 1);
            if (pos >= 0 && pos < E)
                cse[pos] = make_int2(clampi(ei[j], 0, n - 1), __float_as_int(ea[j]));
        }
    }
}

// ---------------------------------------------------------------------------
// Node transform via MFMA, biases folded into the epilogue.
// One wave computes a 16-row x 256-col tile (Q|K|V|S) with 32 MFMAs.
// Outputs: Q f32, KV interleaved bf16 [row][128] (K=0..63, V=64..127), S f32,
// qWe = (Q+bq).We.  INF32: read f32 input and convert in-register.
// ---------------------------------------------------------------------------
template<bool INF32>
__global__ __launch_bounds__(256) void node_transform_mfma(
    const void* __restrict__ xin, const ushort* __restrict__ Bpack,
    const float* __restrict__ We,
    const float* __restrict__ bq, const float* __restrict__ bk,
    const float* __restrict__ bv, const float* __restrict__ bs,
    float* __restrict__ Q, ushort* __restrict__ KVb,
    float* __restrict__ S, float* __restrict__ qWe, int n)
{
    __shared__ bshort8 Blds[2048];    // 32 KiB
    {
        const bshort8* gB = (const bshort8*)Bpack;
        for (int i = threadIdx.x; i < 2048; i += 256) Blds[i] = gB[i];
    }
    __syncthreads();

    int lane = threadIdx.x & 63;
    int wv = threadIdx.x >> 6;
    int tile = blockIdx.x * 4 + wv;
    int ntiles = (n + 15) >> 4;
    if (tile >= ntiles) return;
    int r0 = tile << 4;
    int c = lane & 15, g = lane >> 4;

    int arow = r0 + c; if (arow >= n) arow = n - 1;
    union { ushort4 u[2]; bshort8 v; } A0, A1;
    if constexpr (INF32) {
        const float* xr = (const float*)xin + (size_t)arow * 64 + 4 * g;
        float4 f0 = *(const float4*)(xr);
        float4 f1 = *(const float4*)(xr + 16);
        float4 f2 = *(const float4*)(xr + 32);
        float4 f3 = *(const float4*)(xr + 48);
        A0.u[0] = make_ushort4(f2bf(f0.x), f2bf(f0.y), f2bf(f0.z), f2bf(f0.w));
        A0.u[1] = make_ushort4(f2bf(f1.x), f2bf(f1.y), f2bf(f1.z), f2bf(f1.w));
        A1.u[0] = make_ushort4(f2bf(f2.x), f2bf(f2.y), f2bf(f2.z), f2bf(f2.w));
        A1.u[1] = make_ushort4(f2bf(f3.x), f2bf(f3.y), f2bf(f3.z), f2bf(f3.w));
    } else {
        const ushort* xr = (const ushort*)xin + (size_t)arow * 64 + 4 * g;
        A0.u[0] = *(const ushort4*)(xr);
        A0.u[1] = *(const ushort4*)(xr + 16);
        A1.u[0] = *(const ushort4*)(xr + 32);
        A1.u[1] = *(const ushort4*)(xr + 48);
    }

    f32x4 acc[16];
    #pragma unroll
    for (int t = 0; t < 16; ++t) acc[t] = (f32x4){0.f, 0.f, 0.f, 0.f};
    #pragma unroll
    for (int t = 0; t < 16; ++t) {
        acc[t] = __builtin_amdgcn_mfma_f32_16x16x32_bf16(A0.v, Blds[(2 * t) * 64 + lane], acc[t], 0, 0, 0);
        acc[t] = __builtin_amdgcn_mfma_f32_16x16x32_bf16(A1.v, Blds[(2 * t + 1) * 64 + lane], acc[t], 0, 0, 0);
    }

    float we_c[4], bq_c[4];
    #pragma unroll
    for (int t = 0; t < 4; ++t) { we_c[t] = We[16 * t + c]; bq_c[t] = bq[16 * t + c]; }
    #pragma unroll
    for (int j = 0; j < 4; ++j) {
        float part = 0.f;
        #pragma unroll
        for (int t = 0; t < 4; ++t) part += (acc[t][j] + bq_c[t]) * we_c[t];
        part += __shfl_xor(part, 1);
        part += __shfl_xor(part, 2);
        part += __shfl_xor(part, 4);
        part += __shfl_xor(part, 8);
        int orow = r0 + 4 * g + j;
        if (c == 0 && orow < n) qWe[orow] = part;
    }

    #pragma unroll
    for (int tt = 0; tt < 4; ++tt) {
        int col = 16 * tt + c;
        float vbk = bk[col], vbv = bv[col], vbs = bs[col];
        #pragma unroll
        for (int j = 0; j < 4; ++j) {
            int orow = r0 + 4 * g + j;
            if (orow >= n) continue;
            size_t o = (size_t)orow * 64 + col;
            Q[o] = acc[tt][j] + bq_c[tt];
            KVb[(size_t)orow * 128 + col]      = f2bf(acc[4 + tt][j] + vbk);
            KVb[(size_t)orow * 128 + 64 + col] = f2bf(acc[8 + tt][j] + vbv);
            S[o] = acc[12 + tt][j] + vbs;
        }
    }
}

// ---------------------------------------------------------------------------
// Fused attention aggregate: one 8-lane group per dst node (50k independent
// groups). Per edge: cse int2 broadcast, K+V halves of one 256B row (2x16B
// per lane), 8-wide dot with 3 shuffles, exp computed redundantly per lane,
// shuffle-free accumulate (each lane owns its 8 output columns).
// score = (Q[dst].K[src] + ea*qWe[dst]) / 8; softmax w/o max-subtraction
// (scores are O(1), softmax shift-invariant).
// out = (sum p*V)/sum p + (sum p*ea)/sum p * We + S   (+relu, bf16 for L1).
// ---------------------------------------------------------------------------
template<int L1>
__global__ __launch_bounds__(256) void agg3_kernel(
    const float* __restrict__ Q, const ushort* __restrict__ KVb,
    const float* __restrict__ S, const float* __restrict__ qWe,
    const float* __restrict__ We, const int* __restrict__ row_ptr,
    const int2* __restrict__ cse, void* __restrict__ outp, int n, int E)
{
    int q8 = threadIdx.x & 7;
    int gid = (blockIdx.x * blockDim.x + threadIdx.x) >> 3;
    int ng  = (gridDim.x * blockDim.x) >> 3;
    float4 weA = ((const float4*)We)[2 * q8];
    float4 weB = ((const float4*)We)[2 * q8 + 1];

    for (int i = gid; i < n; i += ng) {
        int beg = clampi(row_ptr[i], 0, E);
        int end = clampi(row_ptr[i + 1], beg, E);
        const float4* Qrow = (const float4*)(Q + (size_t)i * 64);
        float4 qA = Qrow[2 * q8], qB = Qrow[2 * q8 + 1];
        float qwe8 = qWe[i] * 0.125f;
        f32x4 aA = {0.f, 0.f, 0.f, 0.f}, aB = {0.f, 0.f, 0.f, 0.f};
        float ssum = 0.f, sea = 0.f;

        for (int e = beg; e < end; ++e) {
            int2 ed = cse[e];
            int sp = clampi(ed.x, 0, n - 1);
            float ea = __int_as_float(ed.y);
            const ushort* row = KVb + (size_t)sp * 128 + 8 * q8;
            ushort8v k8 = *(const ushort8v*)(row);
            ushort8v v8 = *(const ushort8v*)(row + 64);
            float part = qA.x * bf2f(k8[0]) + qA.y * bf2f(k8[1])
                       + qA.z * bf2f(k8[2]) + qA.w * bf2f(k8[3])
                       + qB.x * bf2f(k8[4]) + qB.y * bf2f(k8[5])
                       + qB.z * bf2f(k8[6]) + qB.w * bf2f(k8[7]);
            part += __shfl_xor(part, 1);
            part += __shfl_xor(part, 2);
            part += __shfl_xor(part, 4);
            float p = __expf(fmaf(ea, qwe8, part * 0.125f));
            ssum += p;
            sea = fmaf(p, ea, sea);
            aA[0] = fmaf(p, bf2f(v8[0]), aA[0]);
            aA[1] = fmaf(p, bf2f(v8[1]), aA[1]);
            aA[2] = fmaf(p, bf2f(v8[2]), aA[2]);
            aA[3] = fmaf(p, bf2f(v8[3]), aA[3]);
            aB[0] = fmaf(p, bf2f(v8[4]), aB[0]);
            aB[1] = fmaf(p, bf2f(v8[5]), aB[1]);
            aB[2] = fmaf(p, bf2f(v8[6]), aB[2]);
            aB[3] = fmaf(p, bf2f(v8[7]), aB[3]);
        }

        float inv = (ssum > 0.f) ? 1.f / ssum : 0.f;
        float eawe = sea * inv;
        const float4* Srow = (const float4*)(S + (size_t)i * 64);
        float4 sA = Srow[2 * q8], sB = Srow[2 * q8 + 1];
        float o0 = fmaf(aA[0], inv, fmaf(eawe, weA.x, sA.x));
        float o1 = fmaf(aA[1], inv, fmaf(eawe, weA.y, sA.y));
        float o2 = fmaf(aA[2], inv, fmaf(eawe, weA.z, sA.z));
        float o3 = fmaf(aA[3], inv, fmaf(eawe, weA.w, sA.w));
        float o4 = fmaf(aB[0], inv, fmaf(eawe, weB.x, sB.x));
        float o5 = fmaf(aB[1], inv, fmaf(eawe, weB.y, sB.y));
        float o6 = fmaf(aB[2], inv, fmaf(eawe, weB.z, sB.z));
        float o7 = fmaf(aB[3], inv, fmaf(eawe, weB.w, sB.w));
        if (L1) {
            o0 = fmaxf(o0, 0.f); o1 = fmaxf(o1, 0.f); o2 = fmaxf(o2, 0.f); o3 = fmaxf(o3, 0.f);
            o4 = fmaxf(o4, 0.f); o5 = fmaxf(o5, 0.f); o6 = fmaxf(o6, 0.f); o7 = fmaxf(o7, 0.f);
            union { ushort u[8]; ushort8v v; } ov;
            ov.u[0] = f2bf(o0); ov.u[1] = f2bf(o1); ov.u[2] = f2bf(o2); ov.u[3] = f2bf(o3);
            ov.u[4] = f2bf(o4); ov.u[5] = f2bf(o5); ov.u[6] = f2bf(o6); ov.u[7] = f2bf(o7);
            *(ushort8v*)((ushort*)outp + (size_t)i * 64 + 8 * q8) = ov.v;
        } else {
            float4* Or = (float4*)((float*)outp + (size_t)i * 64);
            Or[2 * q8]     = make_float4(o0, o1, o2, o3);
            Or[2 * q8 + 1] = make_float4(o4, o5, o6, o7);
        }
    }
}

// ---------------------------------------------------------------------------
extern "C" void kernel_launch(void* const* d_in, const int* in_sizes, int n_in,
                              void* d_out, int out_size, void* d_ws, size_t ws_size,
                              hipStream_t stream) {
    const float* x   = (const float*)d_in[0];
    const int*   ei  = (const int*)d_in[1];     // int32 on device
    const float* ea  = (const float*)d_in[2];
    const float *Wq1 = (const float*)d_in[3],  *bq1 = (const float*)d_in[4];
    const float *Wk1 = (const float*)d_in[5],  *bk1 = (const float*)d_in[6];
    const float *Wv1 = (const float*)d_in[7],  *bv1 = (const float*)d_in[8];
    const float *We1 = (const float*)d_in[9];
    const float *Ws1 = (const float*)d_in[10], *bs1 = (const float*)d_in[11];
    const float *Wq2 = (const float*)d_in[12], *bq2 = (const float*)d_in[13];
    const float *Wk2 = (const float*)d_in[14], *bk2 = (const float*)d_in[15];
    const float *Wv2 = (const float*)d_in[16], *bv2 = (const float*)d_in[17];
    const float *We2 = (const float*)d_in[18];
    const float *Ws2 = (const float*)d_in[19], *bs2 = (const float*)d_in[20];

    const int N_ = in_sizes[0] / 64;   // 50000
    const int E_ = in_sizes[2];        // 800000

    char* wsb = (char*)d_ws;
    size_t off = 0;
    auto carve = [&](size_t bytes) -> void* {
        void* p = (void*)(wsb + off);
        off += (bytes + 255) & ~(size_t)255;
        return p;
    };
    float*  Q    = (float*)carve((size_t)N_ * 64 * 4);
    float*  S    = (float*)carve((size_t)N_ * 64 * 4);
    ushort* KVb  = (ushort*)carve((size_t)N_ * 128 * 2);
    ushort* hb   = (ushort*)carve((size_t)N_ * 64 * 2);
    float*  qWe  = (float*)carve((size_t)N_ * 4);
    int*    count   = (int*)carve((size_t)N_ * 4);
    int*    row_ptr = (int*)carve((size_t)(N_ + 1) * 4);
    int*    cursor  = (int*)carve((size_t)N_ * 4);
    int2*   cse     = (int2*)carve((size_t)E_ * 8);
    ushort* Bp1     = (ushort*)carve(2048 * 8 * 2);
    ushort* Bp2     = (ushort*)carve(2048 * 8 * 2);
    (void)ws_size; (void)n_in; (void)out_size;

    pack_and_zero<<<16 + (N_ + 255) / 256, 256, 0, stream>>>(
        Wq1, Wk1, Wv1, Ws1, Wq2, Wk2, Wv2, Ws2, Bp1, Bp2, count, N_);

    // CSR build
    hist_kernel<<<(E_ + 255) / 256, 256, 0, stream>>>(ei, count, E_, N_);
    scan_exclusive<<<1, 1024, 0, stream>>>(count, row_ptr, cursor, N_);
    scatter_kernel<<<3136, 256, 0, stream>>>(ei, ea, cursor, cse, E_, N_);

    int ntb = (((N_ + 15) / 16) + 3) / 4;

    // Layer 1
    node_transform_mfma<true><<<ntb, 256, 0, stream>>>(x, Bp1, We1, bq1, bk1, bv1, bs1,
                                                       Q, KVb, S, qWe, N_);
    agg3_kernel<1><<<1568, 256, 0, stream>>>(Q, KVb, S, qWe, We1, row_ptr, cse, hb, N_, E_);
    // Layer 2
    node_transform_mfma<false><<<ntb, 256, 0, stream>>>(hb, Bp2, We2, bq2, bk2, bv2, bs2,
                                                        Q, KVb, S, qWe, N_);
    agg3_kernel<0><<<1568, 256, 0, stream>>>(Q, KVb, S, qWe, We2, row_ptr, cse, d_out, N_, E_);
}

// Round 11
// 231.551 us; speedup vs baseline: 4.9272x; 1.0059x over previous
//
#include <hip/hip_runtime.h>
#include <hip/hip_bf16.h>

typedef short bshort8 __attribute__((ext_vector_type(8)));
typedef float f32x4 __attribute__((ext_vector_type(4)));
typedef unsigned short ushort8v __attribute__((ext_vector_type(8)));

__device__ __forceinline__ int clampi(int v, int lo, int hi) {
    return v < lo ? lo : (v > hi ? hi : v);
}
__device__ __forceinline__ ushort f2bf(float f) {           // RNE f32 -> bf16 bits
    uint u = __float_as_uint(f);
    return (ushort)((u + 0x7FFFu + ((u >> 16) & 1u)) >> 16);
}
__device__ __forceinline__ float bf2f(ushort b) { return __uint_as_float(((uint)b) << 16); }

__device__ __forceinline__ float dot8(float4 qA, float4 qB, ushort8v k8) {
    return qA.x * bf2f(k8[0]) + qA.y * bf2f(k8[1]) + qA.z * bf2f(k8[2]) + qA.w * bf2f(k8[3])
         + qB.x * bf2f(k8[4]) + qB.y * bf2f(k8[5]) + qB.z * bf2f(k8[6]) + qB.w * bf2f(k8[7]);
}

// ---------------------------------------------------------------------------
// Pack both layers' weights into per-lane MFMA B-fragments (blocks 0..15) and
// zero the histogram counters (blocks >= 16). One launch instead of two.
// Fragment layout (mfma_f32_16x16x32_bf16): elem i of lane l holds B[k][col],
// col = 16*(t&3)+(l&15), k = 32*h + 16*(i>>2) + 4*(l>>4) + (i&3).
// ---------------------------------------------------------------------------
__global__ void pack_and_zero(const float* __restrict__ Wq1, const float* __restrict__ Wk1,
                              const float* __restrict__ Wv1, const float* __restrict__ Ws1,
                              const float* __restrict__ Wq2, const float* __restrict__ Wk2,
                              const float* __restrict__ Wv2, const float* __restrict__ Ws2,
                              ushort* __restrict__ Bp1, ushort* __restrict__ Bp2,
                              int* __restrict__ count, int n) {
    if (blockIdx.x >= 16) {
        int j = (blockIdx.x - 16) * 256 + threadIdx.x;
        if (j < n) count[j] = 0;
        return;
    }
    int tid = blockIdx.x * 256 + threadIdx.x;          // 0..4095
    int layer = tid >> 11;
    int t2 = tid & 2047;
    int lane = t2 & 63;
    int th = t2 >> 6;                  // t*2 + h
    int h = th & 1, t = th >> 1;
    const float* W = layer ? ((t < 4) ? Wq2 : (t < 8) ? Wk2 : (t < 12) ? Wv2 : Ws2)
                           : ((t < 4) ? Wq1 : (t < 8) ? Wk1 : (t < 12) ? Wv1 : Ws1);
    ushort* Bp = layer ? Bp2 : Bp1;
    int col = ((t & 3) << 4) + (lane & 15);
    int g = lane >> 4;
    #pragma unroll
    for (int i = 0; i < 8; ++i) {
        int k = 32 * h + 16 * (i >> 2) + 4 * g + (i & 3);
        Bp[t2 * 8 + i] = f2bf(W[k * 64 + col]);
    }
}

// ---------------------------------------------------------------------------
// CSR build. hist: plain device-scope atomics (one coalesced pass).
// ---------------------------------------------------------------------------
__global__ void hist_kernel(const int* __restrict__ ei, int* __restrict__ count,
                            int E, int n) {
    int j = blockIdx.x * blockDim.x + threadIdx.x;
    if (j < E) {
        int d = clampi(ei[E + j], 0, n - 1);
        atomicAdd(&count[d], 1);
    }
}

// Exclusive scan, single block of 1024 threads, 4 elements per thread per pass.
__global__ void scan_exclusive(const int* __restrict__ count, int* __restrict__ row_ptr,
                               int* __restrict__ cursor, int n) {
    __shared__ int wsum[16];
    int tid = threadIdx.x, lane = tid & 63, wv = tid >> 6;
    int carry = 0;
    for (int base = 0; base < n; base += 4096) {
        int i4 = base + tid * 4;
        int v0 = 0, v1 = 0, v2 = 0, v3 = 0;
        if (i4 + 3 < n) {
            int4 t = *(const int4*)(count + i4);
            v0 = t.x; v1 = t.y; v2 = t.z; v3 = t.w;
        } else {
            if (i4     < n) v0 = count[i4];
            if (i4 + 1 < n) v1 = count[i4 + 1];
            if (i4 + 2 < n) v2 = count[i4 + 2];
            if (i4 + 3 < n) v3 = count[i4 + 3];
        }
        int s0 = v0, s1 = s0 + v1, s2 = s1 + v2, s3 = s2 + v3;
        int sv = s3;
        #pragma unroll
        for (int off = 1; off < 64; off <<= 1) {
            int t = __shfl_up(sv, off, 64);
            if (lane >= off) sv += t;
        }
        if (lane == 63) wsum[wv] = sv;
        __syncthreads();
        if (tid < 16) {
            int ws = wsum[tid];
            #pragma unroll
            for (int off = 1; off < 16; off <<= 1) {
                int t = __shfl_up(ws, off, 64);
                if (tid >= off) ws += t;
            }
            wsum[tid] = ws;
        }
        __syncthreads();
        int add = carry + (wv ? wsum[wv - 1] : 0) + (sv - s3);
        if (i4     < n) { row_ptr[i4]     = add;      cursor[i4]     = add;      }
        if (i4 + 1 < n) { row_ptr[i4 + 1] = add + s0; cursor[i4 + 1] = add + s0; }
        if (i4 + 2 < n) { row_ptr[i4 + 2] = add + s1; cursor[i4 + 2] = add + s1; }
        if (i4 + 3 < n) { row_ptr[i4 + 3] = add + s2; cursor[i4 + 3] = add + s2; }
        carry += wsum[15];
        __syncthreads();
    }
    if (tid == 0) row_ptr[n] = carry;
}

// Scatter, XCD-sharded: replica r = blockIdx.x & 7 handles dst range
// [r*n/8,(r+1)*n/8) so each CSR region is written from one XCD (write-clean
// 64B lines). Emits int2 {src, ea_bits} per edge (dst is implicit in CSR).
__global__ void scatter_kernel(const int* __restrict__ ei, const float* __restrict__ ea,
                               int* __restrict__ cursor, int2* __restrict__ cse,
                               int E, int n) {
    int r = blockIdx.x & 7;
    int nb = gridDim.x >> 3, cb = blockIdx.x >> 3;
    int rlo = r * n;                       // compare d*8 against [r*n, (r+1)*n)
    for (int j = cb * 256 + threadIdx.x; j < E; j += nb * 256) {
        int d = clampi(ei[E + j], 0, n - 1);
        int d8 = d << 3;
        if (d8 >= rlo && d8 < rlo + n) {
            int pos = atomicAdd(&cursor[d], 1);
            if (pos >= 0 && pos < E)
                cse[pos] = make_int2(clampi(ei[j], 0, n - 1), __float_as_int(ea[j]));
        }
    }
}

// ---------------------------------------------------------------------------
// Node transform via MFMA, biases folded into the epilogue.
// One wave computes a 16-row x 256-col tile (Q|K|V|S) with 32 MFMAs.
// Outputs: Qb bf16, KV interleaved bf16 [row][128] (K=0..63, V=64..127),
// S f32, qWe = (Q+bq).We.  INF32: read f32 input, convert in-register.
// ---------------------------------------------------------------------------
template<bool INF32>
__global__ __launch_bounds__(256) void node_transform_mfma(
    const void* __restrict__ xin, const ushort* __restrict__ Bpack,
    const float* __restrict__ We,
    const float* __restrict__ bq, const float* __restrict__ bk,
    const float* __restrict__ bv, const float* __restrict__ bs,
    ushort* __restrict__ Qb, ushort* __restrict__ KVb,
    float* __restrict__ S, float* __restrict__ qWe, int n)
{
    __shared__ bshort8 Blds[2048];    // 32 KiB
    {
        const bshort8* gB = (const bshort8*)Bpack;
        for (int i = threadIdx.x; i < 2048; i += 256) Blds[i] = gB[i];
    }
    __syncthreads();

    int lane = threadIdx.x & 63;
    int wv = threadIdx.x >> 6;
    int tile = blockIdx.x * 4 + wv;
    int ntiles = (n + 15) >> 4;
    if (tile >= ntiles) return;
    int r0 = tile << 4;
    int c = lane & 15, g = lane >> 4;

    int arow = r0 + c; if (arow >= n) arow = n - 1;
    union { ushort4 u[2]; bshort8 v; } A0, A1;
    if constexpr (INF32) {
        const float* xr = (const float*)xin + (size_t)arow * 64 + 4 * g;
        float4 f0 = *(const float4*)(xr);
        float4 f1 = *(const float4*)(xr + 16);
        float4 f2 = *(const float4*)(xr + 32);
        float4 f3 = *(const float4*)(xr + 48);
        A0.u[0] = make_ushort4(f2bf(f0.x), f2bf(f0.y), f2bf(f0.z), f2bf(f0.w));
        A0.u[1] = make_ushort4(f2bf(f1.x), f2bf(f1.y), f2bf(f1.z), f2bf(f1.w));
        A1.u[0] = make_ushort4(f2bf(f2.x), f2bf(f2.y), f2bf(f2.z), f2bf(f2.w));
        A1.u[1] = make_ushort4(f2bf(f3.x), f2bf(f3.y), f2bf(f3.z), f2bf(f3.w));
    } else {
        const ushort* xr = (const ushort*)xin + (size_t)arow * 64 + 4 * g;
        A0.u[0] = *(const ushort4*)(xr);
        A0.u[1] = *(const ushort4*)(xr + 16);
        A1.u[0] = *(const ushort4*)(xr + 32);
        A1.u[1] = *(const ushort4*)(xr + 48);
    }

    f32x4 acc[16];
    #pragma unroll
    for (int t = 0; t < 16; ++t) acc[t] = (f32x4){0.f, 0.f, 0.f, 0.f};
    #pragma unroll
    for (int t = 0; t < 16; ++t) {
        acc[t] = __builtin_amdgcn_mfma_f32_16x16x32_bf16(A0.v, Blds[(2 * t) * 64 + lane], acc[t], 0, 0, 0);
        acc[t] = __builtin_amdgcn_mfma_f32_16x16x32_bf16(A1.v, Blds[(2 * t + 1) * 64 + lane], acc[t], 0, 0, 0);
    }

    float we_c[4], bq_c[4];
    #pragma unroll
    for (int t = 0; t < 4; ++t) { we_c[t] = We[16 * t + c]; bq_c[t] = bq[16 * t + c]; }
    #pragma unroll
    for (int j = 0; j < 4; ++j) {
        float part = 0.f;
        #pragma unroll
        for (int t = 0; t < 4; ++t) part += (acc[t][j] + bq_c[t]) * we_c[t];
        part += __shfl_xor(part, 1);
        part += __shfl_xor(part, 2);
        part += __shfl_xor(part, 4);
        part += __shfl_xor(part, 8);
        int orow = r0 + 4 * g + j;
        if (c == 0 && orow < n) qWe[orow] = part;
    }

    #pragma unroll
    for (int tt = 0; tt < 4; ++tt) {
        int col = 16 * tt + c;
        float vbk = bk[col], vbv = bv[col], vbs = bs[col];
        #pragma unroll
        for (int j = 0; j < 4; ++j) {
            int orow = r0 + 4 * g + j;
            if (orow >= n) continue;
            size_t o = (size_t)orow * 64 + col;
            Qb[o] = f2bf(acc[tt][j] + bq_c[tt]);
            KVb[(size_t)orow * 128 + col]      = f2bf(acc[4 + tt][j] + vbk);
            KVb[(size_t)orow * 128 + 64 + col] = f2bf(acc[8 + tt][j] + vbv);
            S[o] = acc[12 + tt][j] + vbs;
        }
    }
}

// ---------------------------------------------------------------------------
// Fused attention aggregate: one 8-lane group per dst node (50k independent
// groups). Edge loop manually unrolled x2 with independent load/dot/exp
// chains to double in-flight work (latency-bound kernel). Per edge: cse int2
// broadcast, K+V halves of one 256B row (2x16B per lane), 8-wide dot with 3
// shuffles, exp redundant per lane, shuffle-free accumulate (each lane owns
// its 8 output columns). score = (Q[dst].K[src] + ea*qWe[dst]) / 8; softmax
// w/o max-subtraction (scores O(1), shift-invariant).
// out = (sum p*V)/sum p + (sum p*ea)/sum p * We + S   (+relu, bf16 for L1).
// ---------------------------------------------------------------------------
template<int L1>
__global__ __launch_bounds__(256) void agg3_kernel(
    const ushort* __restrict__ Qb, const ushort* __restrict__ KVb,
    const float* __restrict__ S, const float* __restrict__ qWe,
    const float* __restrict__ We, const int* __restrict__ row_ptr,
    const int2* __restrict__ cse, void* __restrict__ outp, int n, int E)
{
    int q8 = threadIdx.x & 7;
    int gid = (blockIdx.x * blockDim.x + threadIdx.x) >> 3;
    int ng  = (gridDim.x * blockDim.x) >> 3;
    float4 weA = ((const float4*)We)[2 * q8];
    float4 weB = ((const float4*)We)[2 * q8 + 1];

    for (int i = gid; i < n; i += ng) {
        int beg = clampi(row_ptr[i], 0, E);
        int end = clampi(row_ptr[i + 1], beg, E);
        ushort8v q8v = *(const ushort8v*)(Qb + (size_t)i * 64 + 8 * q8);
        float4 qA = make_float4(bf2f(q8v[0]), bf2f(q8v[1]), bf2f(q8v[2]), bf2f(q8v[3]));
        float4 qB = make_float4(bf2f(q8v[4]), bf2f(q8v[5]), bf2f(q8v[6]), bf2f(q8v[7]));
        float qwe8 = qWe[i] * 0.125f;
        f32x4 aA = {0.f, 0.f, 0.f, 0.f}, aB = {0.f, 0.f, 0.f, 0.f};
        float ssum = 0.f, sea = 0.f;

        int e = beg;
        for (; e + 2 <= end; e += 2) {
            int2 ed0 = cse[e], ed1 = cse[e + 1];
            const ushort* r0 = KVb + (size_t)clampi(ed0.x, 0, n - 1) * 128 + 8 * q8;
            const ushort* r1 = KVb + (size_t)clampi(ed1.x, 0, n - 1) * 128 + 8 * q8;
            ushort8v k0 = *(const ushort8v*)(r0);
            ushort8v v0 = *(const ushort8v*)(r0 + 64);
            ushort8v k1 = *(const ushort8v*)(r1);
            ushort8v v1 = *(const ushort8v*)(r1 + 64);
            float ea0 = __int_as_float(ed0.y), ea1 = __int_as_float(ed1.y);
            float d0 = dot8(qA, qB, k0);
            float d1 = dot8(qA, qB, k1);
            d0 += __shfl_xor(d0, 1); d1 += __shfl_xor(d1, 1);
            d0 += __shfl_xor(d0, 2); d1 += __shfl_xor(d1, 2);
            d0 += __shfl_xor(d0, 4); d1 += __shfl_xor(d1, 4);
            float p0 = __expf(fmaf(ea0, qwe8, d0 * 0.125f));
            float p1 = __expf(fmaf(ea1, qwe8, d1 * 0.125f));
            ssum += p0 + p1;
            sea = fmaf(p0, ea0, fmaf(p1, ea1, sea));
            aA[0] = fmaf(p0, bf2f(v0[0]), fmaf(p1, bf2f(v1[0]), aA[0]));
            aA[1] = fmaf(p0, bf2f(v0[1]), fmaf(p1, bf2f(v1[1]), aA[1]));
            aA[2] = fmaf(p0, bf2f(v0[2]), fmaf(p1, bf2f(v1[2]), aA[2]));
            aA[3] = fmaf(p0, bf2f(v0[3]), fmaf(p1, bf2f(v1[3]), aA[3]));
            aB[0] = fmaf(p0, bf2f(v0[4]), fmaf(p1, bf2f(v1[4]), aB[0]));
            aB[1] = fmaf(p0, bf2f(v0[5]), fmaf(p1, bf2f(v1[5]), aB[1]));
            aB[2] = fmaf(p0, bf2f(v0[6]), fmaf(p1, bf2f(v1[6]), aB[2]));
            aB[3] = fmaf(p0, bf2f(v0[7]), fmaf(p1, bf2f(v1[7]), aB[3]));
        }
        if (e < end) {
            int2 ed = cse[e];
            const ushort* row = KVb + (size_t)clampi(ed.x, 0, n - 1) * 128 + 8 * q8;
            ushort8v k0 = *(const ushort8v*)(row);
            ushort8v v0 = *(const ushort8v*)(row + 64);
            float ea0 = __int_as_float(ed.y);
            float d0 = dot8(qA, qB, k0);
            d0 += __shfl_xor(d0, 1);
            d0 += __shfl_xor(d0, 2);
            d0 += __shfl_xor(d0, 4);
            float p0 = __expf(fmaf(ea0, qwe8, d0 * 0.125f));
            ssum += p0;
            sea = fmaf(p0, ea0, sea);
            aA[0] = fmaf(p0, bf2f(v0[0]), aA[0]);
            aA[1] = fmaf(p0, bf2f(v0[1]), aA[1]);
            aA[2] = fmaf(p0, bf2f(v0[2]), aA[2]);
            aA[3] = fmaf(p0, bf2f(v0[3]), aA[3]);
            aB[0] = fmaf(p0, bf2f(v0[4]), aB[0]);
            aB[1] = fmaf(p0, bf2f(v0[5]), aB[1]);
            aB[2] = fmaf(p0, bf2f(v0[6]), aB[2]);
            aB[3] = fmaf(p0, bf2f(v0[7]), aB[3]);
        }

        float inv = (ssum > 0.f) ? 1.f / ssum : 0.f;
        float eawe = sea * inv;
        const float4* Srow = (const float4*)(S + (size_t)i * 64);
        float4 sA = Srow[2 * q8], sB = Srow[2 * q8 + 1];
        float o0 = fmaf(aA[0], inv, fmaf(eawe, weA.x, sA.x));
        float o1 = fmaf(aA[1], inv, fmaf(eawe, weA.y, sA.y));
        float o2 = fmaf(aA[2], inv, fmaf(eawe, weA.z, sA.z));
        float o3 = fmaf(aA[3], inv, fmaf(eawe, weA.w, sA.w));
        float o4 = fmaf(aB[0], inv, fmaf(eawe, weB.x, sB.x));
        float o5 = fmaf(aB[1], inv, fmaf(eawe, weB.y, sB.y));
        float o6 = fmaf(aB[2], inv, fmaf(eawe, weB.z, sB.z));
        float o7 = fmaf(aB[3], inv, fmaf(eawe, weB.w, sB.w));
        if (L1) {
            o0 = fmaxf(o0, 0.f); o1 = fmaxf(o1, 0.f); o2 = fmaxf(o2, 0.f); o3 = fmaxf(o3, 0.f);
            o4 = fmaxf(o4, 0.f); o5 = fmaxf(o5, 0.f); o6 = fmaxf(o6, 0.f); o7 = fmaxf(o7, 0.f);
            union { ushort u[8]; ushort8v v; } ov;
            ov.u[0] = f2bf(o0); ov.u[1] = f2bf(o1); ov.u[2] = f2bf(o2); ov.u[3] = f2bf(o3);
            ov.u[4] = f2bf(o4); ov.u[5] = f2bf(o5); ov.u[6] = f2bf(o6); ov.u[7] = f2bf(o7);
            *(ushort8v*)((ushort*)outp + (size_t)i * 64 + 8 * q8) = ov.v;
        } else {
            float4* Or = (float4*)((float*)outp + (size_t)i * 64);
            Or[2 * q8]     = make_float4(o0, o1, o2, o3);
            Or[2 * q8 + 1] = make_float4(o4, o5, o6, o7);
        }
    }
}

// ---------------------------------------------------------------------------
extern "C" void kernel_launch(void* const* d_in, const int* in_sizes, int n_in,
                              void* d_out, int out_size, void* d_ws, size_t ws_size,
                              hipStream_t stream) {
    const float* x   = (const float*)d_in[0];
    const int*   ei  = (const int*)d_in[1];     // int32 on device
    const float* ea  = (const float*)d_in[2];
    const float *Wq1 = (const float*)d_in[3],  *bq1 = (const float*)d_in[4];
    const float *Wk1 = (const float*)d_in[5],  *bk1 = (const float*)d_in[6];
    const float *Wv1 = (const float*)d_in[7],  *bv1 = (const float*)d_in[8];
    const float *We1 = (const float*)d_in[9];
    const float *Ws1 = (const float*)d_in[10], *bs1 = (const float*)d_in[11];
    const float *Wq2 = (const float*)d_in[12], *bq2 = (const float*)d_in[13];
    const float *Wk2 = (const float*)d_in[14], *bk2 = (const float*)d_in[15];
    const float *Wv2 = (const float*)d_in[16], *bv2 = (const float*)d_in[17];
    const float *We2 = (const float*)d_in[18];
    const float *Ws2 = (const float*)d_in[19], *bs2 = (const float*)d_in[20];

    const int N_ = in_sizes[0] / 64;   // 50000
    const int E_ = in_sizes[2];        // 800000

    char* wsb = (char*)d_ws;
    size_t off = 0;
    auto carve = [&](size_t bytes) -> void* {
        void* p = (void*)(wsb + off);
        off += (bytes + 255) & ~(size_t)255;
        return p;
    };
    ushort* Qb   = (ushort*)carve((size_t)N_ * 64 * 2);
    float*  S    = (float*)carve((size_t)N_ * 64 * 4);
    ushort* KVb  = (ushort*)carve((size_t)N_ * 128 * 2);
    ushort* hb   = (ushort*)carve((size_t)N_ * 64 * 2);
    float*  qWe  = (float*)carve((size_t)N_ * 4);
    int*    count   = (int*)carve((size_t)N_ * 4);
    int*    row_ptr = (int*)carve((size_t)(N_ + 1) * 4);
    int*    cursor  = (int*)carve((size_t)N_ * 4);
    int2*   cse     = (int2*)carve((size_t)E_ * 8);
    ushort* Bp1     = (ushort*)carve(2048 * 8 * 2);
    ushort* Bp2     = (ushort*)carve(2048 * 8 * 2);
    (void)ws_size; (void)n_in; (void)out_size;

    pack_and_zero<<<16 + (N_ + 255) / 256, 256, 0, stream>>>(
        Wq1, Wk1, Wv1, Ws1, Wq2, Wk2, Wv2, Ws2, Bp1, Bp2, count, N_);

    // CSR build
    hist_kernel<<<(E_ + 255) / 256, 256, 0, stream>>>(ei, count, E_, N_);
    scan_exclusive<<<1, 1024, 0, stream>>>(count, row_ptr, cursor, N_);
    scatter_kernel<<<3136, 256, 0, stream>>>(ei, ea, cursor, cse, E_, N_);

    int ntb = (((N_ + 15) / 16) + 3) / 4;

    // Layer 1
    node_transform_mfma<true><<<ntb, 256, 0, stream>>>(x, Bp1, We1, bq1, bk1, bv1, bs1,
                                                       Qb, KVb, S, qWe, N_);
    agg3_kernel<1><<<1568, 256, 0, stream>>>(Qb, KVb, S, qWe, We1, row_ptr, cse, hb, N_, E_);
    // Layer 2
    node_transform_mfma<false><<<ntb, 256, 0, stream>>>(hb, Bp2, We2, bq2, bk2, bv2, bs2,
                                                        Qb, KVb, S, qWe, N_);
    agg3_kernel<0><<<1568, 256, 0, stream>>>(Qb, KVb, S, qWe, We2, row_ptr, cse, d_out, N_, E_);
}